// Round 1
// baseline (804.991 us; speedup 1.0000x reference)
//
#include <hip/hip_runtime.h>
#include <math.h>

#define N_CELLS   100000
#define N_CLASSES 50
#define N_GENES   500
#define N_EDGES   600000
#define HID       8
#define CPAD      64   // classes padded to 64 lanes

// ---- workspace layout (bytes) ----
static const size_t OFF_INVVT = 0;               // [G/4][64][4] f32 packed, 128000 B
static const size_t OFF_MUIVT = 128000;          // same, 128000 B
static const size_t OFF_T3    = 256000;          // 64 f32
static const size_t OFF_GLR   = 262144;          // [N][16] f32, 6.4 MB (16B aligned)
static const size_t OFF_SCORE = 6662144;         // [E] f32
static const size_t OFF_MSEG  = 9062144;         // [N] u32 (mapped max)
static const size_t OFF_DENOM = 9462144;         // [N] f32
static const size_t OFF_NUMER = 9862144;         // [N] f32
static const size_t OFF_LL    = 10262144;        // double
static const size_t OFF_CE    = 10262152;        // double
static const size_t ZERO_BEG  = OFF_MSEG;
static const size_t ZERO_BYTES= 10262160 - 9062144;

// ---------- prep: invV^T and (Mu*invV)^T in g-packed layout ----------
// packed index for (g,c): (g>>2)*(CPAD*4) + c*4 + (g&3)
__global__ void k_prep(const float* __restrict__ Var, const float* __restrict__ Mu,
                       float* __restrict__ invVT, float* __restrict__ muivT) {
    int id = blockIdx.x * 256 + threadIdx.x;     // 0 .. 32000
    int g = id >> 6, c = id & 63;
    if (g >= N_GENES) return;
    float iv = 0.f, mi = 0.f;
    if (c < N_CLASSES) {
        float v = Var[c * N_GENES + g];
        iv = 1.0f / v;
        mi = Mu[c * N_GENES + g] * iv;
    }
    int idx = (g >> 2) * (CPAD * 4) + c * 4 + (g & 3);
    invVT[idx] = iv;
    muivT[idx] = mi;
}

__global__ void k_t3(const float* __restrict__ Var, const float* __restrict__ Mu,
                     float* __restrict__ t3) {
    int c = threadIdx.x;          // one block of 64
    float s = 0.f;
    if (c < N_CLASSES) {
        for (int g = 0; g < N_GENES; ++g) {
            float m = Mu[c * N_GENES + g];
            s += m * m / Var[c * N_GENES + g];
        }
    }
    t3[c] = s;                    // lanes >= 50 write 0
}

// ---------- row softmax: P = softmax(W, axis=1), wave per row ----------
__global__ __launch_bounds__(256) void k_softmax(const float* __restrict__ W,
                                                 float* __restrict__ P) {
    int wid  = (blockIdx.x * 256 + threadIdx.x) >> 6;
    int lane = threadIdx.x & 63;
    if (wid >= N_CELLS) return;
    float w = (lane < N_CLASSES) ? W[(size_t)wid * N_CLASSES + lane] : -__builtin_inff();
    float m = w;
    #pragma unroll
    for (int off = 32; off; off >>= 1) m = fmaxf(m, __shfl_xor(m, off));
    float e = (lane < N_CLASSES) ? expf(w - m) : 0.f;
    float s = e;
    #pragma unroll
    for (int off = 32; off; off >>= 1) s += __shfl_xor(s, off);
    if (lane < N_CLASSES) P[(size_t)wid * N_CLASSES + lane] = e / s;
}

// ---------- Gaussian LL: wave = 50 class-lanes x 8 rows ----------
__global__ __launch_bounds__(256) void k_gauss(const float* __restrict__ X,
                                               const float* __restrict__ S,
                                               const float* __restrict__ P,
                                               const float* __restrict__ invVT,
                                               const float* __restrict__ muivT,
                                               const float* __restrict__ t3,
                                               double* __restrict__ ll_acc) {
    int lane = threadIdx.x & 63;
    int wv   = threadIdx.x >> 6;
    int base = blockIdx.x * 32 + wv * 8;          // 8 rows per wave, 32 per block
    const float4* iv4 = (const float4*)invVT;     // [(G/4)*64] float4
    const float4* mi4 = (const float4*)muivT;

    float t1[8], t2[8];
    #pragma unroll
    for (int r = 0; r < 8; ++r) { t1[r] = 0.f; t2[r] = 0.f; }

    const float* Xb = X + (size_t)base * N_GENES;
    for (int g = 0; g < N_GENES; g += 4) {
        float4 i1 = iv4[(g >> 2) * CPAD + lane];
        float4 i2 = mi4[(g >> 2) * CPAD + lane];
        float4 xa[8];
        #pragma unroll
        for (int r = 0; r < 8; ++r)
            xa[r] = *(const float4*)(Xb + r * N_GENES + g);
        #pragma unroll
        for (int r = 0; r < 8; ++r) {
            float x0 = xa[r].x, x1 = xa[r].y, x2 = xa[r].z, x3 = xa[r].w;
            t1[r] = fmaf(x0 * x0, i1.x, t1[r]);
            t1[r] = fmaf(x1 * x1, i1.y, t1[r]);
            t1[r] = fmaf(x2 * x2, i1.z, t1[r]);
            t1[r] = fmaf(x3 * x3, i1.w, t1[r]);
            t2[r] = fmaf(x0, i2.x, t2[r]);
            t2[r] = fmaf(x1, i2.y, t2[r]);
            t2[r] = fmaf(x2, i2.z, t2[r]);
            t2[r] = fmaf(x3, i2.w, t2[r]);
        }
    }

    float t3v = t3[lane];
    float part = 0.f;
    #pragma unroll
    for (int r = 0; r < 8; ++r) {
        int n = base + r;
        float sv = S[n];
        float F  = -0.5f * (t1[r] - 2.f * sv * t2[r] + sv * sv * t3v);
        float p  = (lane < N_CLASSES) ? P[(size_t)n * N_CLASSES + lane] : 0.f;
        part = fmaf(p, F, part);
    }
    #pragma unroll
    for (int off = 32; off; off >>= 1) part += __shfl_xor(part, off);
    if (lane == 0) atomicAdd(ll_acc, (double)part);
}

// ---------- gl/gr projection: thread per row, weights in LDS ----------
__global__ __launch_bounds__(256) void k_glgr(const float* __restrict__ X,
                                              const float* __restrict__ wl,
                                              const float* __restrict__ bl,
                                              const float* __restrict__ wr,
                                              const float* __restrict__ br,
                                              float* __restrict__ glr) {
    __shared__ float wlds[N_GENES][16];
    for (int i = threadIdx.x; i < N_GENES * HID; i += 256) {
        int h = i / N_GENES;
        int g = i - h * N_GENES;
        wlds[g][h]     = wl[i];
        wlds[g][h + 8] = wr[i];
    }
    __syncthreads();
    int n = blockIdx.x * 256 + threadIdx.x;
    if (n >= N_CELLS) return;

    float acc[16];
    #pragma unroll
    for (int h = 0; h < 16; ++h) acc[h] = 0.f;
    const float* xr = X + (size_t)n * N_GENES;
    for (int g = 0; g < N_GENES; g += 4) {
        float4 x = *(const float4*)(xr + g);
        #pragma unroll
        for (int h = 0; h < 16; ++h) {
            acc[h] = fmaf(x.x, wlds[g][h],     acc[h]);
            acc[h] = fmaf(x.y, wlds[g + 1][h], acc[h]);
            acc[h] = fmaf(x.z, wlds[g + 2][h], acc[h]);
            acc[h] = fmaf(x.w, wlds[g + 3][h], acc[h]);
        }
    }
    #pragma unroll
    for (int h = 0; h < 8; ++h) { acc[h] += bl[h]; acc[h + 8] += br[h]; }
    float4* out = (float4*)(glr + (size_t)n * 16);
    out[0] = make_float4(acc[0], acc[1], acc[2], acc[3]);
    out[1] = make_float4(acc[4], acc[5], acc[6], acc[7]);
    out[2] = make_float4(acc[8], acc[9], acc[10], acc[11]);
    out[3] = make_float4(acc[12], acc[13], acc[14], acc[15]);
}

// ---------- edge scores + segment max (mapped-uint atomicMax) ----------
__device__ __forceinline__ unsigned map_f32(float f) {
    int s = __float_as_int(f);
    return (s < 0) ? ~(unsigned)s : ((unsigned)s | 0x80000000u);
}
__device__ __forceinline__ float unmap_f32(unsigned u) {
    return (u & 0x80000000u) ? __int_as_float((int)(u & 0x7fffffffu))
                             : __int_as_float((int)~u);
}

__global__ __launch_bounds__(256) void k_score(const int* __restrict__ ei,
                                               const float* __restrict__ glr,
                                               const float* __restrict__ att,
                                               float* __restrict__ score,
                                               unsigned* __restrict__ mseg) {
    int e = blockIdx.x * 256 + threadIdx.x;
    if (e >= N_EDGES) return;
    int src = ei[e], dst = ei[N_EDGES + e];
    const float4* a = (const float4*)(glr + (size_t)src * 16);       // gl
    const float4* b = (const float4*)(glr + (size_t)dst * 16 + 8);   // gr
    float4 g0 = a[0], g1 = a[1], h0 = b[0], h1 = b[1];
    const float4* at = (const float4*)att;
    float4 a0 = at[0], a1 = at[1];
    float v, s = 0.f;
    v = g0.x + h0.x; v = v > 0.f ? v : 0.2f * v; s = fmaf(a0.x, v, s);
    v = g0.y + h0.y; v = v > 0.f ? v : 0.2f * v; s = fmaf(a0.y, v, s);
    v = g0.z + h0.z; v = v > 0.f ? v : 0.2f * v; s = fmaf(a0.z, v, s);
    v = g0.w + h0.w; v = v > 0.f ? v : 0.2f * v; s = fmaf(a0.w, v, s);
    v = g1.x + h1.x; v = v > 0.f ? v : 0.2f * v; s = fmaf(a1.x, v, s);
    v = g1.y + h1.y; v = v > 0.f ? v : 0.2f * v; s = fmaf(a1.y, v, s);
    v = g1.z + h1.z; v = v > 0.f ? v : 0.2f * v; s = fmaf(a1.z, v, s);
    v = g1.w + h1.w; v = v > 0.f ? v : 0.2f * v; s = fmaf(a1.w, v, s);
    score[e] = s;
    atomicMax(mseg + dst, map_f32(s));
}

// ---------- fused exp/segment-sum/CE gather: wave per edge ----------
__global__ __launch_bounds__(256) void k_edge2(const int* __restrict__ ei,
                                               const float* __restrict__ score,
                                               const unsigned* __restrict__ mseg,
                                               const float* __restrict__ P,
                                               float* __restrict__ denom,
                                               float* __restrict__ numer) {
    int wid  = (blockIdx.x * 256 + threadIdx.x) >> 6;
    int lane = threadIdx.x & 63;
    if (wid >= N_EDGES) return;
    int src = ei[wid], dst = ei[N_EDGES + wid];
    float m  = unmap_f32(mseg[dst]);
    float ex = expf(score[wid] - m);
    float v = 0.f;
    if (lane < N_CLASSES) {
        float ps = P[(size_t)src * N_CLASSES + lane];
        float pd = P[(size_t)dst * N_CLASSES + lane];
        v = ps * logf(pd + 1e-8f);
    }
    #pragma unroll
    for (int off = 32; off; off >>= 1) v += __shfl_xor(v, off);
    if (lane == 0) {
        atomicAdd(denom + dst, ex);
        atomicAdd(numer + dst, ex * v);
    }
}

// ---------- CE node reduce ----------
__global__ __launch_bounds__(256) void k_ce(const float* __restrict__ denom,
                                            const float* __restrict__ numer,
                                            double* __restrict__ ce_acc) {
    int n = blockIdx.x * 256 + threadIdx.x;
    float v = 0.f;
    if (n < N_CELLS) {
        float d = denom[n];
        v = (d > 0.f) ? numer[n] / d : 0.f;
    }
    #pragma unroll
    for (int off = 32; off; off >>= 1) v += __shfl_xor(v, off);
    if ((threadIdx.x & 63) == 0) atomicAdd(ce_acc, (double)v);
}

__global__ void k_final(const double* __restrict__ ll, const double* __restrict__ ce,
                        float* __restrict__ out) {
    out[0] = (float)(*ll / (double)N_CELLS);
    out[1] = (float)(-(*ce) / (double)N_CELLS);
}

extern "C" void kernel_launch(void* const* d_in, const int* in_sizes, int n_in,
                              void* d_out, int out_size, void* d_ws, size_t ws_size,
                              hipStream_t stream) {
    const float* X   = (const float*)d_in[0];
    const float* Mu  = (const float*)d_in[1];
    const float* Var = (const float*)d_in[2];
    const float* W   = (const float*)d_in[3];
    const float* S   = (const float*)d_in[4];
    const int*   ei  = (const int*)d_in[5];
    const float* wl  = (const float*)d_in[6];
    const float* bl  = (const float*)d_in[7];
    const float* wr  = (const float*)d_in[8];
    const float* br  = (const float*)d_in[9];
    const float* att = (const float*)d_in[10];
    float* out = (float*)d_out;
    char*  ws  = (char*)d_ws;

    float*    invVT = (float*)(ws + OFF_INVVT);
    float*    muivT = (float*)(ws + OFF_MUIVT);
    float*    t3    = (float*)(ws + OFF_T3);
    float*    glr   = (float*)(ws + OFF_GLR);
    float*    score = (float*)(ws + OFF_SCORE);
    unsigned* mseg  = (unsigned*)(ws + OFF_MSEG);
    float*    denom = (float*)(ws + OFF_DENOM);
    float*    numer = (float*)(ws + OFF_NUMER);
    double*   ll_acc= (double*)(ws + OFF_LL);
    double*   ce_acc= (double*)(ws + OFF_CE);
    float*    P     = out + 2;

    hipMemsetAsync(ws + ZERO_BEG, 0, ZERO_BYTES, stream);

    k_prep   <<<125, 256, 0, stream>>>(Var, Mu, invVT, muivT);
    k_t3     <<<1, 64, 0, stream>>>(Var, Mu, t3);
    k_softmax<<<(N_CELLS * 64 + 255) / 256, 256, 0, stream>>>(W, P);
    k_glgr   <<<(N_CELLS + 255) / 256, 256, 0, stream>>>(X, wl, bl, wr, br, glr);
    k_gauss  <<<N_CELLS / 32, 256, 0, stream>>>(X, S, P, invVT, muivT, t3, ll_acc);
    k_score  <<<(N_EDGES + 255) / 256, 256, 0, stream>>>(ei, glr, att, score, mseg);
    k_edge2  <<<(N_EDGES * 64) / 256, 256, 0, stream>>>(ei, score, mseg, P, denom, numer);
    k_ce     <<<(N_CELLS + 255) / 256, 256, 0, stream>>>(denom, numer, ce_acc);
    k_final  <<<1, 1, 0, stream>>>(ll_acc, ce_acc, out);
}

// Round 2
// 368.511 us; speedup vs baseline: 2.1844x; 2.1844x over previous
//
#include <hip/hip_runtime.h>
#include <math.h>

#define N_CELLS   100000
#define N_CLASSES 50
#define N_GENES   500
#define N_EDGES   600000
#define HID       8
#define KP        512
#define NSTEP     16   // KP/32
#define NTILE     9    // 4 invV col-tiles + 4 MuinvV col-tiles + 1 [wl;wr] tile

typedef __attribute__((ext_vector_type(4))) float f32x4;
typedef __attribute__((ext_vector_type(8))) short bf16x8;

// ---- workspace layout (bytes) ----
static const size_t OFF_BF    = 0;                 // 9*16*64*16 = 147456 B bf16 B-fragments
static const size_t OFF_T3    = 147456;            // 64 f32
static const size_t OFF_GLR   = 147712;            // [N][16] f32, 6.4 MB
static const size_t OFF_SCORE = 6547712;           // [E] f32, 2.4 MB
static const size_t OFF_MSEG  = 8947712;           // [N] u32 (mapped max)
static const size_t OFF_DENOM = 9347712;           // [N] f32
static const size_t OFF_NUMER = 9747712;           // [N] f32
static const size_t OFF_LL    = 10147712;          // double
static const size_t OFF_CE    = 10147720;          // double
static const size_t ZERO_BEG  = OFF_MSEG;
static const size_t ZERO_BYTES= 10147728 - 8947712;

__device__ __forceinline__ ushort f2bf(float f) {
    union { float f; unsigned u; } v; v.f = f;
    unsigned r = v.u + 0x7fffu + ((v.u >> 16) & 1u);   // RNE
    return (ushort)(r >> 16);
}

// ---------- prep: B fragments in MFMA layout ----------
// frag element id = ((tile*16 + s)*64 + lane)*8 + j ; k = s*32 + (lane>>4)*8 + j
__global__ __launch_bounds__(256) void k_prepB(const float* __restrict__ Var,
                                               const float* __restrict__ Mu,
                                               const float* __restrict__ wl,
                                               const float* __restrict__ wr,
                                               ushort* __restrict__ Bf) {
    int id = blockIdx.x * 256 + threadIdx.x;           // 73728 total, exact grid
    int j    = id & 7;
    int lane = (id >> 3) & 63;
    int s    = (id >> 9) & 15;
    int t    = id >> 13;
    int k = s * 32 + ((lane >> 4) << 3) + j;
    float v = 0.f;
    if (k < N_GENES) {
        if (t < 4) {
            int c = t * 16 + (lane & 15);
            if (c < N_CLASSES) v = 1.0f / Var[c * N_GENES + k];
        } else if (t < 8) {
            int c = (t - 4) * 16 + (lane & 15);
            if (c < N_CLASSES) v = Mu[c * N_GENES + k] / Var[c * N_GENES + k];
        } else {
            int h = lane & 15;
            v = (h < HID) ? wl[h * N_GENES + k] : wr[(h - HID) * N_GENES + k];
        }
    }
    Bf[id] = f2bf(v);
}

__global__ void k_t3(const float* __restrict__ Var, const float* __restrict__ Mu,
                     float* __restrict__ t3) {
    int c = threadIdx.x;          // one block of 64
    float s = 0.f;
    if (c < N_CLASSES) {
        for (int g = 0; g < N_GENES; ++g) {
            float m = Mu[c * N_GENES + g];
            s += m * m / Var[c * N_GENES + g];
        }
    }
    t3[c] = s;
}

// ---------- row softmax: P = softmax(W, axis=1), wave per row ----------
__global__ __launch_bounds__(256) void k_softmax(const float* __restrict__ W,
                                                 float* __restrict__ P) {
    int wid  = (blockIdx.x * 256 + threadIdx.x) >> 6;
    int lane = threadIdx.x & 63;
    if (wid >= N_CELLS) return;
    float w = (lane < N_CLASSES) ? W[(size_t)wid * N_CLASSES + lane] : -__builtin_inff();
    float m = w;
    #pragma unroll
    for (int off = 32; off; off >>= 1) m = fmaxf(m, __shfl_xor(m, off));
    float e = (lane < N_CLASSES) ? expf(w - m) : 0.f;
    float s = e;
    #pragma unroll
    for (int off = 32; off; off >>= 1) s += __shfl_xor(s, off);
    if (lane < N_CLASSES) P[(size_t)wid * N_CLASSES + lane] = e / s;
}

// ---------- fused MFMA: Gaussian LL + gl/gr projection ----------
// wave = 16 rows; A1 = bf16(X^2), A2 = bf16(-2S*X); acc3/A2 gives -2S*(X@[wl;wr]^T)
__global__ __launch_bounds__(256) void k_fused(const float* __restrict__ X,
                                               const float* __restrict__ S,
                                               const float* __restrict__ P,
                                               const ushort* __restrict__ Bf,
                                               const float* __restrict__ t3,
                                               const float* __restrict__ bl,
                                               const float* __restrict__ br,
                                               float* __restrict__ glr,
                                               double* __restrict__ ll_acc) {
    int lane  = threadIdx.x & 63;
    int wv    = threadIdx.x >> 6;
    int rbase = blockIdx.x * 64 + wv * 16;
    int arow  = rbase + (lane & 15);
    if (arow >= N_CELLS) arow = N_CELLS - 1;
    float sv  = S[arow];
    float m2s = -2.0f * sv;
    const float* xp0 = X + (size_t)arow * N_GENES;
    int kgrp = (lane >> 4) << 3;

    const f32x4 zz = {0.f, 0.f, 0.f, 0.f};
    f32x4 acc1[4], acc2[4], acc3;
    #pragma unroll
    for (int ct = 0; ct < 4; ++ct) { acc1[ct] = zz; acc2[ct] = zz; }
    acc3 = zz;

    #pragma unroll 2
    for (int s = 0; s < NSTEP; ++s) {
        int koff = s * 32 + kgrp;
        f32x4 xa = zz, xb = zz;
        if (koff <= N_GENES - 4) xa = *(const f32x4*)(xp0 + koff);
        if (koff <= N_GENES - 12) xb = *(const f32x4*)(xp0 + koff + 4);
        bf16x8 a1, a2;
        #pragma unroll
        for (int j = 0; j < 4; ++j) {
            float x = xa[j];
            a1[j]     = (short)f2bf(x * x);
            a2[j]     = (short)f2bf(m2s * x);
            float y = xb[j];
            a1[j + 4] = (short)f2bf(y * y);
            a2[j + 4] = (short)f2bf(m2s * y);
        }
        const bf16x8* Bp = ((const bf16x8*)Bf) + (size_t)s * 64 + lane;
        #pragma unroll
        for (int ct = 0; ct < 4; ++ct)
            acc1[ct] = __builtin_amdgcn_mfma_f32_16x16x32_bf16(a1, Bp[(size_t)ct * 1024], acc1[ct], 0, 0, 0);
        #pragma unroll
        for (int ct = 0; ct < 4; ++ct)
            acc2[ct] = __builtin_amdgcn_mfma_f32_16x16x32_bf16(a2, Bp[(size_t)(4 + ct) * 1024], acc2[ct], 0, 0, 0);
        acc3 = __builtin_amdgcn_mfma_f32_16x16x32_bf16(a2, Bp[(size_t)8 * 1024], acc3, 0, 0, 0);
    }

    // ---- epilogue: C/D layout col=lane&15, row=(lane>>4)*4+reg ----
    int col = lane & 15;
    int rg  = lane >> 4;
    float bias = (col < HID) ? bl[col] : br[col - HID];
    float part = 0.f;
    #pragma unroll
    for (int r = 0; r < 4; ++r) {
        int row = rbase + rg * 4 + r;
        if (row < N_CELLS) {
            float s2 = S[row];
            glr[(size_t)row * 16 + col] = acc3[r] / (-2.0f * s2) + bias;
            float ss = s2 * s2;
            #pragma unroll
            for (int ct = 0; ct < 4; ++ct) {
                int c = ct * 16 + col;
                if (c < N_CLASSES) {
                    float F = -0.5f * (acc1[ct][r] + acc2[ct][r] + ss * t3[c]);
                    part = fmaf(P[(size_t)row * N_CLASSES + c], F, part);
                }
            }
        }
    }
    #pragma unroll
    for (int off = 32; off; off >>= 1) part += __shfl_xor(part, off);
    if (lane == 0) atomicAdd(ll_acc, (double)part);
}

// ---------- edge scores + segment max (mapped-uint atomicMax) ----------
__device__ __forceinline__ unsigned map_f32(float f) {
    int s = __float_as_int(f);
    return (s < 0) ? ~(unsigned)s : ((unsigned)s | 0x80000000u);
}
__device__ __forceinline__ float unmap_f32(unsigned u) {
    return (u & 0x80000000u) ? __int_as_float((int)(u & 0x7fffffffu))
                             : __int_as_float((int)~u);
}

__global__ __launch_bounds__(256) void k_score(const int* __restrict__ ei,
                                               const float* __restrict__ glr,
                                               const float* __restrict__ att,
                                               float* __restrict__ score,
                                               unsigned* __restrict__ mseg) {
    int e = blockIdx.x * 256 + threadIdx.x;
    if (e >= N_EDGES) return;
    int src = ei[e], dst = ei[N_EDGES + e];
    const float4* a = (const float4*)(glr + (size_t)src * 16);       // gl
    const float4* b = (const float4*)(glr + (size_t)dst * 16 + 8);   // gr
    float4 g0 = a[0], g1 = a[1], h0 = b[0], h1 = b[1];
    const float4* at = (const float4*)att;
    float4 a0 = at[0], a1 = at[1];
    float v, s = 0.f;
    v = g0.x + h0.x; v = v > 0.f ? v : 0.2f * v; s = fmaf(a0.x, v, s);
    v = g0.y + h0.y; v = v > 0.f ? v : 0.2f * v; s = fmaf(a0.y, v, s);
    v = g0.z + h0.z; v = v > 0.f ? v : 0.2f * v; s = fmaf(a0.z, v, s);
    v = g0.w + h0.w; v = v > 0.f ? v : 0.2f * v; s = fmaf(a0.w, v, s);
    v = g1.x + h1.x; v = v > 0.f ? v : 0.2f * v; s = fmaf(a1.x, v, s);
    v = g1.y + h1.y; v = v > 0.f ? v : 0.2f * v; s = fmaf(a1.y, v, s);
    v = g1.z + h1.z; v = v > 0.f ? v : 0.2f * v; s = fmaf(a1.z, v, s);
    v = g1.w + h1.w; v = v > 0.f ? v : 0.2f * v; s = fmaf(a1.w, v, s);
    score[e] = s;
    atomicMax(mseg + dst, map_f32(s));
}

// ---------- fused exp/segment-sum/CE gather: wave per edge ----------
__global__ __launch_bounds__(256) void k_edge2(const int* __restrict__ ei,
                                               const float* __restrict__ score,
                                               const unsigned* __restrict__ mseg,
                                               const float* __restrict__ P,
                                               float* __restrict__ denom,
                                               float* __restrict__ numer) {
    int wid  = (blockIdx.x * 256 + threadIdx.x) >> 6;
    int lane = threadIdx.x & 63;
    if (wid >= N_EDGES) return;
    int src = ei[wid], dst = ei[N_EDGES + wid];
    float m  = unmap_f32(mseg[dst]);
    float ex = expf(score[wid] - m);
    float v = 0.f;
    if (lane < N_CLASSES) {
        float ps = P[(size_t)src * N_CLASSES + lane];
        float pd = P[(size_t)dst * N_CLASSES + lane];
        v = ps * logf(pd + 1e-8f);
    }
    #pragma unroll
    for (int off = 32; off; off >>= 1) v += __shfl_xor(v, off);
    if (lane == 0) {
        atomicAdd(denom + dst, ex);
        atomicAdd(numer + dst, ex * v);
    }
}

// ---------- CE node reduce ----------
__global__ __launch_bounds__(256) void k_ce(const float* __restrict__ denom,
                                            const float* __restrict__ numer,
                                            double* __restrict__ ce_acc) {
    int n = blockIdx.x * 256 + threadIdx.x;
    float v = 0.f;
    if (n < N_CELLS) {
        float d = denom[n];
        v = (d > 0.f) ? numer[n] / d : 0.f;
    }
    #pragma unroll
    for (int off = 32; off; off >>= 1) v += __shfl_xor(v, off);
    if ((threadIdx.x & 63) == 0) atomicAdd(ce_acc, (double)v);
}

__global__ void k_final(const double* __restrict__ ll, const double* __restrict__ ce,
                        float* __restrict__ out) {
    out[0] = (float)(*ll / (double)N_CELLS);
    out[1] = (float)(-(*ce) / (double)N_CELLS);
}

extern "C" void kernel_launch(void* const* d_in, const int* in_sizes, int n_in,
                              void* d_out, int out_size, void* d_ws, size_t ws_size,
                              hipStream_t stream) {
    const float* X   = (const float*)d_in[0];
    const float* Mu  = (const float*)d_in[1];
    const float* Var = (const float*)d_in[2];
    const float* W   = (const float*)d_in[3];
    const float* S   = (const float*)d_in[4];
    const int*   ei  = (const int*)d_in[5];
    const float* wl  = (const float*)d_in[6];
    const float* bl  = (const float*)d_in[7];
    const float* wr  = (const float*)d_in[8];
    const float* br  = (const float*)d_in[9];
    const float* att = (const float*)d_in[10];
    float* out = (float*)d_out;
    char*  ws  = (char*)d_ws;

    ushort*   Bf    = (ushort*)(ws + OFF_BF);
    float*    t3    = (float*)(ws + OFF_T3);
    float*    glr   = (float*)(ws + OFF_GLR);
    float*    score = (float*)(ws + OFF_SCORE);
    unsigned* mseg  = (unsigned*)(ws + OFF_MSEG);
    float*    denom = (float*)(ws + OFF_DENOM);
    float*    numer = (float*)(ws + OFF_NUMER);
    double*   ll_acc= (double*)(ws + OFF_LL);
    double*   ce_acc= (double*)(ws + OFF_CE);
    float*    P     = out + 2;

    hipMemsetAsync(ws + ZERO_BEG, 0, ZERO_BYTES, stream);

    k_prepB  <<<288, 256, 0, stream>>>(Var, Mu, wl, wr, Bf);
    k_t3     <<<1, 64, 0, stream>>>(Var, Mu, t3);
    k_softmax<<<(N_CELLS * 64 + 255) / 256, 256, 0, stream>>>(W, P);
    k_fused  <<<(N_CELLS + 63) / 64, 256, 0, stream>>>(X, S, P, Bf, t3, bl, br, glr, ll_acc);
    k_score  <<<(N_EDGES + 255) / 256, 256, 0, stream>>>(ei, glr, att, score, mseg);
    k_edge2  <<<(N_EDGES * 64) / 256, 256, 0, stream>>>(ei, score, mseg, P, denom, numer);
    k_ce     <<<(N_CELLS + 255) / 256, 256, 0, stream>>>(denom, numer, ce_acc);
    k_final  <<<1, 1, 0, stream>>>(ll_acc, ce_acc, out);
}

// Round 3
// 295.617 us; speedup vs baseline: 2.7231x; 1.2466x over previous
//
#include <hip/hip_runtime.h>
#include <math.h>

#define N_CELLS   100000
#define N_CLASSES 50
#define N_GENES   500
#define N_EDGES   600000
#define HID       8
#define NKT       8    // K tiles of 64 floats (512 padded)
#define NSTEP     16   // MFMA k-steps of 32

typedef __attribute__((ext_vector_type(4))) float f32x4;
typedef __attribute__((ext_vector_type(8))) short bf16x8;

// ---- workspace layout (bytes) ----
static const size_t OFF_BF    = 0;                 // 9*16*64*16 = 147456 B bf16 B-fragments
static const size_t OFF_T3    = 147456;            // 64 f32
static const size_t OFF_GLR   = 147712;            // [N][16] f32, 6.4 MB
static const size_t OFF_SCORE = 6547712;           // [E] f32, 2.4 MB
static const size_t OFF_MSEG  = 8947712;           // [N] u32 (mapped max)
static const size_t OFF_DENOM = 9347712;           // [N] f32
static const size_t OFF_NUMER = 9747712;           // [N] f32
static const size_t OFF_LL    = 10147712;          // double
static const size_t OFF_CE    = 10147720;          // double
static const size_t ZERO_BEG  = OFF_MSEG;
static const size_t ZERO_BYTES= 10147728 - 8947712;

__device__ __forceinline__ ushort f2bf(float f) {
    union { float f; unsigned u; } v; v.f = f;
    unsigned r = v.u + 0x7fffu + ((v.u >> 16) & 1u);   // RNE
    return (ushort)(r >> 16);
}

__device__ __forceinline__ void gload16(const void* g, void* l) {
    __builtin_amdgcn_global_load_lds(
        (const __attribute__((address_space(1))) unsigned int*)g,
        (__attribute__((address_space(3))) unsigned int*)l,
        16, 0, 0);
}

// ---------- prep: B fragments in MFMA layout ----------
// frag element id = ((tile*16 + s)*64 + lane)*8 + j ; k = s*32 + (lane>>4)*8 + j
__global__ __launch_bounds__(256) void k_prepB(const float* __restrict__ Var,
                                               const float* __restrict__ Mu,
                                               const float* __restrict__ wl,
                                               const float* __restrict__ wr,
                                               ushort* __restrict__ Bf) {
    int id = blockIdx.x * 256 + threadIdx.x;           // 73728 total, exact grid
    int j    = id & 7;
    int lane = (id >> 3) & 63;
    int s    = (id >> 9) & 15;
    int t    = id >> 13;
    int k = s * 32 + ((lane >> 4) << 3) + j;
    float v = 0.f;
    if (k < N_GENES) {
        if (t < 4) {
            int c = t * 16 + (lane & 15);
            if (c < N_CLASSES) v = 1.0f / Var[c * N_GENES + k];
        } else if (t < 8) {
            int c = (t - 4) * 16 + (lane & 15);
            if (c < N_CLASSES) v = Mu[c * N_GENES + k] / Var[c * N_GENES + k];
        } else {
            int h = lane & 15;
            v = (h < HID) ? wl[h * N_GENES + k] : wr[(h - HID) * N_GENES + k];
        }
    }
    Bf[id] = f2bf(v);
}

// ---------- t3: block per class, wave-parallel over genes ----------
__global__ void k_t3(const float* __restrict__ Var, const float* __restrict__ Mu,
                     float* __restrict__ t3) {
    int c = blockIdx.x;
    int lane = threadIdx.x;
    float s = 0.f;
    for (int g = lane; g < N_GENES; g += 64) {
        float m = Mu[c * N_GENES + g];
        s += m * m / Var[c * N_GENES + g];
    }
    #pragma unroll
    for (int off = 32; off; off >>= 1) s += __shfl_xor(s, off);
    if (lane == 0) t3[c] = s;
}

// ---------- row softmax: P = softmax(W, axis=1), wave per row ----------
__global__ __launch_bounds__(256) void k_softmax(const float* __restrict__ W,
                                                 float* __restrict__ P) {
    int wid  = (blockIdx.x * 256 + threadIdx.x) >> 6;
    int lane = threadIdx.x & 63;
    if (wid >= N_CELLS) return;
    float w = (lane < N_CLASSES) ? W[(size_t)wid * N_CLASSES + lane] : -__builtin_inff();
    float m = w;
    #pragma unroll
    for (int off = 32; off; off >>= 1) m = fmaxf(m, __shfl_xor(m, off));
    float e = (lane < N_CLASSES) ? expf(w - m) : 0.f;
    float s = e;
    #pragma unroll
    for (int off = 32; off; off >>= 1) s += __shfl_xor(s, off);
    if (lane < N_CLASSES) P[(size_t)wid * N_CLASSES + lane] = e / s;
}

// ---------- fused MFMA: Gaussian LL + gl/gr projection ----------
// Block = 4 waves x 16 rows = 64 rows. A staged in LDS via global_load_lds
// (granule-XOR swizzled on the GLOBAL SOURCE side, linear LDS dest),
// double-buffered, one barrier per K-tile of 64 floats.
__global__ __launch_bounds__(256) void k_fused(const float* __restrict__ X,
                                               const float* __restrict__ S,
                                               const float* __restrict__ P,
                                               const ushort* __restrict__ Bf,
                                               const float* __restrict__ t3,
                                               const float* __restrict__ bl,
                                               const float* __restrict__ br,
                                               float* __restrict__ glr,
                                               double* __restrict__ ll_acc) {
    __shared__ float ldsA[2][4][16][16][4];   // [buf][wave][row][slot][4 f32] = 32 KB
    int tid  = threadIdx.x;
    int lane = tid & 63;
    int wv   = tid >> 6;
    int lhi  = lane >> 4;
    int slot = lane & 15;
    int rbase = blockIdx.x * 64;
    const char* Xc = (const char*)X;

    int arow = rbase + wv * 16 + (lane & 15);
    if (arow > N_CELLS - 1) arow = N_CELLS - 1;
    float sv  = S[arow];
    float m2s = -2.0f * sv;

    const f32x4 zz = {0.f, 0.f, 0.f, 0.f};
    f32x4 acc1[4], acc2[4], acc3;
    #pragma unroll
    for (int ct = 0; ct < 4; ++ct) { acc1[ct] = zz; acc2[ct] = zz; }
    acc3 = zz;

    // ---- stage kt=0 into buf 0 ----
    #pragma unroll
    for (int i = 0; i < 4; ++i) {
        int rloc = i * 4 + lhi;
        int row  = rbase + wv * 16 + rloc; if (row > N_CELLS - 1) row = N_CELLS - 1;
        int gi   = slot ^ (rloc & 7); if (gi > 124) gi = 124;   // kt=0: base 0
        gload16(Xc + (size_t)row * 2000 + (size_t)gi * 16, &ldsA[0][wv][i * 4][0][0]);
    }

    int cur = 0;
    for (int kt = 0; kt < NKT; ++kt) {
        __syncthreads();                       // buf[cur] ready (drains vmcnt+lgkmcnt)
        if (kt < NKT - 1) {
            int nxt = cur ^ 1;
            #pragma unroll
            for (int i = 0; i < 4; ++i) {
                int rloc = i * 4 + lhi;
                int row  = rbase + wv * 16 + rloc; if (row > N_CELLS - 1) row = N_CELLS - 1;
                int gi   = (kt + 1) * 16 + (slot ^ (rloc & 7)); if (gi > 124) gi = 124;
                gload16(Xc + (size_t)row * 2000 + (size_t)gi * 16, &ldsA[nxt][wv][i * 4][0][0]);
            }
        }
        #pragma unroll
        for (int ks = 0; ks < 2; ++ks) {
            int s    = kt * 2 + ks;
            int rloc = lane & 15, key = rloc & 7;
            int g8   = ks * 8 + lhi * 2;
            f32x4 xa = *(const f32x4*)&ldsA[cur][wv][rloc][g8 ^ key][0];
            f32x4 xb = *(const f32x4*)&ldsA[cur][wv][rloc][(g8 + 1) ^ key][0];
            bf16x8 a1, a2;
            #pragma unroll
            for (int j = 0; j < 4; ++j) {
                float x = xa[j];
                a1[j]     = (short)f2bf(x * x);
                a2[j]     = (short)f2bf(m2s * x);
                float y = xb[j];
                a1[j + 4] = (short)f2bf(y * y);
                a2[j + 4] = (short)f2bf(m2s * y);
            }
            const bf16x8* Bp = ((const bf16x8*)Bf) + (size_t)s * 64 + lane;
            #pragma unroll
            for (int ct = 0; ct < 4; ++ct)
                acc1[ct] = __builtin_amdgcn_mfma_f32_16x16x32_bf16(a1, Bp[(size_t)ct * 1024], acc1[ct], 0, 0, 0);
            #pragma unroll
            for (int ct = 0; ct < 4; ++ct)
                acc2[ct] = __builtin_amdgcn_mfma_f32_16x16x32_bf16(a2, Bp[(size_t)(4 + ct) * 1024], acc2[ct], 0, 0, 0);
            acc3 = __builtin_amdgcn_mfma_f32_16x16x32_bf16(a2, Bp[(size_t)8 * 1024], acc3, 0, 0, 0);
        }
        cur ^= 1;
    }

    // ---- epilogue: C/D layout col=lane&15, row=(lane>>4)*4+reg ----
    int col = lane & 15;
    int rg  = lane >> 4;
    float bias = (col < HID) ? bl[col] : br[col - HID];
    float part = 0.f;
    #pragma unroll
    for (int r = 0; r < 4; ++r) {
        int row = rbase + wv * 16 + rg * 4 + r;
        if (row < N_CELLS) {
            float s2 = S[row];
            glr[(size_t)row * 16 + col] = acc3[r] / (-2.0f * s2) + bias;
            float ss = s2 * s2;
            #pragma unroll
            for (int ct = 0; ct < 4; ++ct) {
                int c = ct * 16 + col;
                if (c < N_CLASSES) {
                    float F = -0.5f * (acc1[ct][r] + acc2[ct][r] + ss * t3[c]);
                    part = fmaf(P[(size_t)row * N_CLASSES + c], F, part);
                }
            }
        }
    }
    #pragma unroll
    for (int off = 32; off; off >>= 1) part += __shfl_xor(part, off);
    if (lane == 0) atomicAdd(ll_acc, (double)part);
}

// ---------- edge scores + segment max (mapped-uint atomicMax) ----------
__device__ __forceinline__ unsigned map_f32(float f) {
    int s = __float_as_int(f);
    return (s < 0) ? ~(unsigned)s : ((unsigned)s | 0x80000000u);
}
__device__ __forceinline__ float unmap_f32(unsigned u) {
    return (u & 0x80000000u) ? __int_as_float((int)(u & 0x7fffffffu))
                             : __int_as_float((int)~u);
}

__global__ __launch_bounds__(256) void k_score(const int* __restrict__ ei,
                                               const float* __restrict__ glr,
                                               const float* __restrict__ att,
                                               float* __restrict__ score,
                                               unsigned* __restrict__ mseg) {
    int e = blockIdx.x * 256 + threadIdx.x;
    if (e >= N_EDGES) return;
    int src = ei[e], dst = ei[N_EDGES + e];
    const float4* a = (const float4*)(glr + (size_t)src * 16);       // gl
    const float4* b = (const float4*)(glr + (size_t)dst * 16 + 8);   // gr
    float4 g0 = a[0], g1 = a[1], h0 = b[0], h1 = b[1];
    const float4* at = (const float4*)att;
    float4 a0 = at[0], a1 = at[1];
    float v, s = 0.f;
    v = g0.x + h0.x; v = v > 0.f ? v : 0.2f * v; s = fmaf(a0.x, v, s);
    v = g0.y + h0.y; v = v > 0.f ? v : 0.2f * v; s = fmaf(a0.y, v, s);
    v = g0.z + h0.z; v = v > 0.f ? v : 0.2f * v; s = fmaf(a0.z, v, s);
    v = g0.w + h0.w; v = v > 0.f ? v : 0.2f * v; s = fmaf(a0.w, v, s);
    v = g1.x + h1.x; v = v > 0.f ? v : 0.2f * v; s = fmaf(a1.x, v, s);
    v = g1.y + h1.y; v = v > 0.f ? v : 0.2f * v; s = fmaf(a1.y, v, s);
    v = g1.z + h1.z; v = v > 0.f ? v : 0.2f * v; s = fmaf(a1.z, v, s);
    v = g1.w + h1.w; v = v > 0.f ? v : 0.2f * v; s = fmaf(a1.w, v, s);
    score[e] = s;
    atomicMax(mseg + dst, map_f32(s));
}

// ---------- fused exp/segment-sum/CE gather: 16 lanes per edge ----------
__global__ __launch_bounds__(256) void k_edge2(const int* __restrict__ ei,
                                               const float* __restrict__ score,
                                               const unsigned* __restrict__ mseg,
                                               const float* __restrict__ P,
                                               float* __restrict__ denom,
                                               float* __restrict__ numer) {
    int t = blockIdx.x * 256 + threadIdx.x;
    int e = t >> 4;
    int q = t & 15;
    if (e >= N_EDGES) return;
    int src = ei[e], dst = ei[N_EDGES + e];
    float ex = expf(score[e] - unmap_f32(mseg[dst]));
    const float* Ps = P + (size_t)src * N_CLASSES;
    const float* Pd = P + (size_t)dst * N_CLASSES;
    float v = Ps[q]      * logf(Pd[q]      + 1e-8f)
            + Ps[q + 16] * logf(Pd[q + 16] + 1e-8f)
            + Ps[q + 32] * logf(Pd[q + 32] + 1e-8f);
    if (q < 2) v += Ps[q + 48] * logf(Pd[q + 48] + 1e-8f);
    v += __shfl_xor(v, 8); v += __shfl_xor(v, 4);
    v += __shfl_xor(v, 2); v += __shfl_xor(v, 1);
    if (q == 0) {
        atomicAdd(denom + dst, ex);
        atomicAdd(numer + dst, ex * v);
    }
}

// ---------- CE node reduce ----------
__global__ __launch_bounds__(256) void k_ce(const float* __restrict__ denom,
                                            const float* __restrict__ numer,
                                            double* __restrict__ ce_acc) {
    int n = blockIdx.x * 256 + threadIdx.x;
    float v = 0.f;
    if (n < N_CELLS) {
        float d = denom[n];
        v = (d > 0.f) ? numer[n] / d : 0.f;
    }
    #pragma unroll
    for (int off = 32; off; off >>= 1) v += __shfl_xor(v, off);
    if ((threadIdx.x & 63) == 0) atomicAdd(ce_acc, (double)v);
}

__global__ void k_final(const double* __restrict__ ll, const double* __restrict__ ce,
                        float* __restrict__ out) {
    out[0] = (float)(*ll / (double)N_CELLS);
    out[1] = (float)(-(*ce) / (double)N_CELLS);
}

extern "C" void kernel_launch(void* const* d_in, const int* in_sizes, int n_in,
                              void* d_out, int out_size, void* d_ws, size_t ws_size,
                              hipStream_t stream) {
    const float* X   = (const float*)d_in[0];
    const float* Mu  = (const float*)d_in[1];
    const float* Var = (const float*)d_in[2];
    const float* W   = (const float*)d_in[3];
    const float* S   = (const float*)d_in[4];
    const int*   ei  = (const int*)d_in[5];
    const float* wl  = (const float*)d_in[6];
    const float* bl  = (const float*)d_in[7];
    const float* wr  = (const float*)d_in[8];
    const float* br  = (const float*)d_in[9];
    const float* att = (const float*)d_in[10];
    float* out = (float*)d_out;
    char*  ws  = (char*)d_ws;

    ushort*   Bf    = (ushort*)(ws + OFF_BF);
    float*    t3    = (float*)(ws + OFF_T3);
    float*    glr   = (float*)(ws + OFF_GLR);
    float*    score = (float*)(ws + OFF_SCORE);
    unsigned* mseg  = (unsigned*)(ws + OFF_MSEG);
    float*    denom = (float*)(ws + OFF_DENOM);
    float*    numer = (float*)(ws + OFF_NUMER);
    double*   ll_acc= (double*)(ws + OFF_LL);
    double*   ce_acc= (double*)(ws + OFF_CE);
    float*    P     = out + 2;

    hipMemsetAsync(ws + ZERO_BEG, 0, ZERO_BYTES, stream);

    k_prepB  <<<288, 256, 0, stream>>>(Var, Mu, wl, wr, Bf);
    k_t3     <<<N_CLASSES, 64, 0, stream>>>(Var, Mu, t3);
    k_softmax<<<(N_CELLS * 64 + 255) / 256, 256, 0, stream>>>(W, P);
    k_fused  <<<(N_CELLS + 63) / 64, 256, 0, stream>>>(X, S, P, Bf, t3, bl, br, glr, ll_acc);
    k_score  <<<(N_EDGES + 255) / 256, 256, 0, stream>>>(ei, glr, att, score, mseg);
    k_edge2  <<<(N_EDGES * 16 + 255) / 256, 256, 0, stream>>>(ei, score, mseg, P, denom, numer);
    k_ce     <<<(N_CELLS + 255) / 256, 256, 0, stream>>>(denom, numer, ce_acc);
    k_final  <<<1, 1, 0, stream>>>(ll_acc, ce_acc, out);
}

// Round 4
// 238.726 us; speedup vs baseline: 3.3720x; 1.2383x over previous
//
#include <hip/hip_runtime.h>
#include <math.h>

#define N_CELLS   100000
#define N_CLASSES 50
#define N_GENES   500
#define N_EDGES   600000
#define HID       8
#define NKT       8    // K tiles of 64 floats (512 padded)
#define NB_FUSED  1563 // (N_CELLS+63)/64
#define NB_CE     391  // (N_CELLS+255)/256

typedef __attribute__((ext_vector_type(4))) float f32x4;
typedef __attribute__((ext_vector_type(8))) short bf16x8;

// ---- workspace layout (bytes) ----
static const size_t OFF_BF    = 0;                 // 147456 B bf16 B-fragments
static const size_t OFF_T3    = 147456;            // 64 f32
static const size_t OFF_GLR   = 147712;            // [N][16] f32, 6.4 MB
static const size_t OFF_SCORE = 6547712;           // [E] f32, 2.4 MB
static const size_t OFF_MSEG  = 8947712;           // [N] u32 (mapped max)
static const size_t OFF_DENOM = 9347712;           // [N] f32
static const size_t OFF_NUMER = 9747712;           // [N] f32
static const size_t OFF_LLP   = 10147712;          // [NB_FUSED] f32 partials
static const size_t OFF_CEP   = 10153968;          // [NB_CE] f32 partials
static const size_t ZERO_BEG  = OFF_MSEG;
static const size_t ZERO_BYTES= 10147712 - 8947712;   // mseg+denom+numer only

__device__ __forceinline__ ushort f2bf(float f) {
    union { float f; unsigned u; } v; v.f = f;
    unsigned r = v.u + 0x7fffu + ((v.u >> 16) & 1u);   // RNE
    return (ushort)(r >> 16);
}

__device__ __forceinline__ unsigned cvt_pk_bf16(float lo, float hi) {
    unsigned r;
    asm("v_cvt_pk_bf16_f32 %0, %1, %2" : "=v"(r) : "v"(lo), "v"(hi));
    return r;
}

__device__ __forceinline__ void gload16(const void* g, void* l) {
    __builtin_amdgcn_global_load_lds(
        (const __attribute__((address_space(1))) unsigned int*)g,
        (__attribute__((address_space(3))) unsigned int*)l,
        16, 0, 0);
}

// ---------- prep: B fragments in MFMA layout ----------
__global__ __launch_bounds__(256) void k_prepB(const float* __restrict__ Var,
                                               const float* __restrict__ Mu,
                                               const float* __restrict__ wl,
                                               const float* __restrict__ wr,
                                               ushort* __restrict__ Bf) {
    int id = blockIdx.x * 256 + threadIdx.x;           // 73728 total, exact grid
    int j    = id & 7;
    int lane = (id >> 3) & 63;
    int s    = (id >> 9) & 15;
    int t    = id >> 13;
    int k = s * 32 + ((lane >> 4) << 3) + j;
    float v = 0.f;
    if (k < N_GENES) {
        if (t < 4) {
            int c = t * 16 + (lane & 15);
            if (c < N_CLASSES) v = 1.0f / Var[c * N_GENES + k];
        } else if (t < 8) {
            int c = (t - 4) * 16 + (lane & 15);
            if (c < N_CLASSES) v = Mu[c * N_GENES + k] / Var[c * N_GENES + k];
        } else {
            int h = lane & 15;
            v = (h < HID) ? wl[h * N_GENES + k] : wr[(h - HID) * N_GENES + k];
        }
    }
    Bf[id] = f2bf(v);
}

// ---------- t3: block per class, wave-parallel over genes ----------
__global__ void k_t3(const float* __restrict__ Var, const float* __restrict__ Mu,
                     float* __restrict__ t3) {
    int c = blockIdx.x;
    int lane = threadIdx.x;
    float s = 0.f;
    for (int g = lane; g < N_GENES; g += 64) {
        float m = Mu[c * N_GENES + g];
        s += m * m / Var[c * N_GENES + g];
    }
    #pragma unroll
    for (int off = 32; off; off >>= 1) s += __shfl_xor(s, off);
    if (lane == 0) t3[c] = s;
}

// ---------- row softmax ----------
__global__ __launch_bounds__(256) void k_softmax(const float* __restrict__ W,
                                                 float* __restrict__ P) {
    int wid  = (blockIdx.x * 256 + threadIdx.x) >> 6;
    int lane = threadIdx.x & 63;
    if (wid >= N_CELLS) return;
    float w = (lane < N_CLASSES) ? W[(size_t)wid * N_CLASSES + lane] : -__builtin_inff();
    float m = w;
    #pragma unroll
    for (int off = 32; off; off >>= 1) m = fmaxf(m, __shfl_xor(m, off));
    float e = (lane < N_CLASSES) ? expf(w - m) : 0.f;
    float s = e;
    #pragma unroll
    for (int off = 32; off; off >>= 1) s += __shfl_xor(s, off);
    if (lane < N_CLASSES) P[(size_t)wid * N_CLASSES + lane] = e / s;
}

// ---------- fused MFMA: Gaussian LL + gl/gr projection ----------
// Per-block partial into llp[blockIdx] (NO same-address global atomics).
__global__ __launch_bounds__(256) void k_fused(const float* __restrict__ X,
                                               const float* __restrict__ S,
                                               const float* __restrict__ P,
                                               const ushort* __restrict__ Bf,
                                               const float* __restrict__ t3,
                                               const float* __restrict__ bl,
                                               const float* __restrict__ br,
                                               float* __restrict__ glr,
                                               float* __restrict__ llp) {
    __shared__ float ldsA[2][4][16][16][4];   // 32 KB
    __shared__ float wsum[4];
    int tid  = threadIdx.x;
    int lane = tid & 63;
    int wv   = tid >> 6;
    int lhi  = lane >> 4;
    int slot = lane & 15;
    int rbase = blockIdx.x * 64;
    const char* Xc = (const char*)X;

    int arow = rbase + wv * 16 + (lane & 15);
    if (arow > N_CELLS - 1) arow = N_CELLS - 1;
    float sv  = S[arow];
    float m2s = -2.0f * sv;

    const f32x4 zz = {0.f, 0.f, 0.f, 0.f};
    f32x4 acc1[4], acc2[4], acc3;
    #pragma unroll
    for (int ct = 0; ct < 4; ++ct) { acc1[ct] = zz; acc2[ct] = zz; }
    acc3 = zz;

    // ---- stage kt=0 into buf 0 ----
    #pragma unroll
    for (int i = 0; i < 4; ++i) {
        int rloc = i * 4 + lhi;
        int row  = rbase + wv * 16 + rloc; if (row > N_CELLS - 1) row = N_CELLS - 1;
        int gi   = slot ^ (rloc & 7); if (gi > 124) gi = 124;
        gload16(Xc + (size_t)row * 2000 + (size_t)gi * 16, &ldsA[0][wv][i * 4][0][0]);
    }

    int cur = 0;
    for (int kt = 0; kt < NKT; ++kt) {
        __syncthreads();
        if (kt < NKT - 1) {
            int nxt = cur ^ 1;
            #pragma unroll
            for (int i = 0; i < 4; ++i) {
                int rloc = i * 4 + lhi;
                int row  = rbase + wv * 16 + rloc; if (row > N_CELLS - 1) row = N_CELLS - 1;
                int gi   = (kt + 1) * 16 + (slot ^ (rloc & 7)); if (gi > 124) gi = 124;
                gload16(Xc + (size_t)row * 2000 + (size_t)gi * 16, &ldsA[nxt][wv][i * 4][0][0]);
            }
        }
        #pragma unroll
        for (int ks = 0; ks < 2; ++ks) {
            int s    = kt * 2 + ks;
            int rloc = lane & 15, key = rloc & 7;
            int g8   = ks * 8 + lhi * 2;
            f32x4 xa = *(const f32x4*)&ldsA[cur][wv][rloc][g8 ^ key][0];
            f32x4 xb = *(const f32x4*)&ldsA[cur][wv][rloc][(g8 + 1) ^ key][0];
            union { bf16x8 v; unsigned u[4]; } a1, a2;
            a1.u[0] = cvt_pk_bf16(xa[0] * xa[0], xa[1] * xa[1]);
            a1.u[1] = cvt_pk_bf16(xa[2] * xa[2], xa[3] * xa[3]);
            a1.u[2] = cvt_pk_bf16(xb[0] * xb[0], xb[1] * xb[1]);
            a1.u[3] = cvt_pk_bf16(xb[2] * xb[2], xb[3] * xb[3]);
            a2.u[0] = cvt_pk_bf16(m2s * xa[0], m2s * xa[1]);
            a2.u[1] = cvt_pk_bf16(m2s * xa[2], m2s * xa[3]);
            a2.u[2] = cvt_pk_bf16(m2s * xb[0], m2s * xb[1]);
            a2.u[3] = cvt_pk_bf16(m2s * xb[2], m2s * xb[3]);
            const bf16x8* Bp = ((const bf16x8*)Bf) + (size_t)s * 64 + lane;
            #pragma unroll
            for (int ct = 0; ct < 4; ++ct)
                acc1[ct] = __builtin_amdgcn_mfma_f32_16x16x32_bf16(a1.v, Bp[(size_t)ct * 1024], acc1[ct], 0, 0, 0);
            #pragma unroll
            for (int ct = 0; ct < 4; ++ct)
                acc2[ct] = __builtin_amdgcn_mfma_f32_16x16x32_bf16(a2.v, Bp[(size_t)(4 + ct) * 1024], acc2[ct], 0, 0, 0);
            acc3 = __builtin_amdgcn_mfma_f32_16x16x32_bf16(a2.v, Bp[(size_t)8 * 1024], acc3, 0, 0, 0);
        }
        cur ^= 1;
    }

    // ---- epilogue ----
    int col = lane & 15;
    int rg  = lane >> 4;
    float bias = (col < HID) ? bl[col] : br[col - HID];
    float part = 0.f;
    #pragma unroll
    for (int r = 0; r < 4; ++r) {
        int row = rbase + wv * 16 + rg * 4 + r;
        if (row < N_CELLS) {
            float s2 = S[row];
            glr[(size_t)row * 16 + col] = acc3[r] / (-2.0f * s2) + bias;
            float ss = s2 * s2;
            #pragma unroll
            for (int ct = 0; ct < 4; ++ct) {
                int c = ct * 16 + col;
                if (c < N_CLASSES) {
                    float F = -0.5f * (acc1[ct][r] + acc2[ct][r] + ss * t3[c]);
                    part = fmaf(P[(size_t)row * N_CLASSES + c], F, part);
                }
            }
        }
    }
    #pragma unroll
    for (int off = 32; off; off >>= 1) part += __shfl_xor(part, off);
    if (lane == 0) wsum[wv] = part;
    __syncthreads();
    if (tid == 0) llp[blockIdx.x] = wsum[0] + wsum[1] + wsum[2] + wsum[3];
}

// ---------- edge scores + segment max ----------
__device__ __forceinline__ unsigned map_f32(float f) {
    int s = __float_as_int(f);
    return (s < 0) ? ~(unsigned)s : ((unsigned)s | 0x80000000u);
}
__device__ __forceinline__ float unmap_f32(unsigned u) {
    return (u & 0x80000000u) ? __int_as_float((int)(u & 0x7fffffffu))
                             : __int_as_float((int)~u);
}

__global__ __launch_bounds__(256) void k_score(const int* __restrict__ ei,
                                               const float* __restrict__ glr,
                                               const float* __restrict__ att,
                                               float* __restrict__ score,
                                               unsigned* __restrict__ mseg) {
    int e = blockIdx.x * 256 + threadIdx.x;
    if (e >= N_EDGES) return;
    int src = ei[e], dst = ei[N_EDGES + e];
    const float4* a = (const float4*)(glr + (size_t)src * 16);       // gl
    const float4* b = (const float4*)(glr + (size_t)dst * 16 + 8);   // gr
    float4 g0 = a[0], g1 = a[1], h0 = b[0], h1 = b[1];
    const float4* at = (const float4*)att;
    float4 a0 = at[0], a1 = at[1];
    float v, s = 0.f;
    v = g0.x + h0.x; v = v > 0.f ? v : 0.2f * v; s = fmaf(a0.x, v, s);
    v = g0.y + h0.y; v = v > 0.f ? v : 0.2f * v; s = fmaf(a0.y, v, s);
    v = g0.z + h0.z; v = v > 0.f ? v : 0.2f * v; s = fmaf(a0.z, v, s);
    v = g0.w + h0.w; v = v > 0.f ? v : 0.2f * v; s = fmaf(a0.w, v, s);
    v = g1.x + h1.x; v = v > 0.f ? v : 0.2f * v; s = fmaf(a1.x, v, s);
    v = g1.y + h1.y; v = v > 0.f ? v : 0.2f * v; s = fmaf(a1.y, v, s);
    v = g1.z + h1.z; v = v > 0.f ? v : 0.2f * v; s = fmaf(a1.z, v, s);
    v = g1.w + h1.w; v = v > 0.f ? v : 0.2f * v; s = fmaf(a1.w, v, s);
    score[e] = s;
    atomicMax(mseg + dst, map_f32(s));
}

// ---------- fused exp/segment-sum/CE gather: 16 lanes per edge ----------
__global__ __launch_bounds__(256) void k_edge2(const int* __restrict__ ei,
                                               const float* __restrict__ score,
                                               const unsigned* __restrict__ mseg,
                                               const float* __restrict__ P,
                                               float* __restrict__ denom,
                                               float* __restrict__ numer) {
    int t = blockIdx.x * 256 + threadIdx.x;
    int e = t >> 4;
    int q = t & 15;
    if (e >= N_EDGES) return;
    int src = ei[e], dst = ei[N_EDGES + e];
    float ex = expf(score[e] - unmap_f32(mseg[dst]));
    const float* Ps = P + (size_t)src * N_CLASSES;
    const float* Pd = P + (size_t)dst * N_CLASSES;
    float v = Ps[q]      * logf(Pd[q]      + 1e-8f)
            + Ps[q + 16] * logf(Pd[q + 16] + 1e-8f)
            + Ps[q + 32] * logf(Pd[q + 32] + 1e-8f);
    if (q < 2) v += Ps[q + 48] * logf(Pd[q + 48] + 1e-8f);
    v += __shfl_xor(v, 8); v += __shfl_xor(v, 4);
    v += __shfl_xor(v, 2); v += __shfl_xor(v, 1);
    if (q == 0) {
        atomicAdd(denom + dst, ex);
        atomicAdd(numer + dst, ex * v);
    }
}

// ---------- CE node reduce -> per-block partial ----------
__global__ __launch_bounds__(256) void k_ce(const float* __restrict__ denom,
                                            const float* __restrict__ numer,
                                            float* __restrict__ cep) {
    __shared__ float wsum[4];
    int n = blockIdx.x * 256 + threadIdx.x;
    float v = 0.f;
    if (n < N_CELLS) {
        float d = denom[n];
        v = (d > 0.f) ? numer[n] / d : 0.f;
    }
    #pragma unroll
    for (int off = 32; off; off >>= 1) v += __shfl_xor(v, off);
    if ((threadIdx.x & 63) == 0) wsum[threadIdx.x >> 6] = v;
    __syncthreads();
    if (threadIdx.x == 0) cep[blockIdx.x] = wsum[0] + wsum[1] + wsum[2] + wsum[3];
}

// ---------- final: reduce partials in f64, write scalars ----------
__global__ __launch_bounds__(256) void k_reduce(const float* __restrict__ llp,
                                                const float* __restrict__ cep,
                                                float* __restrict__ out) {
    __shared__ double l1[256], l2[256];
    int t = threadIdx.x;
    double s1 = 0.0, s2 = 0.0;
    for (int i = t; i < NB_FUSED; i += 256) s1 += (double)llp[i];
    for (int i = t; i < NB_CE; i += 256) s2 += (double)cep[i];
    l1[t] = s1; l2[t] = s2;
    __syncthreads();
    for (int off = 128; off; off >>= 1) {
        if (t < off) { l1[t] += l1[t + off]; l2[t] += l2[t + off]; }
        __syncthreads();
    }
    if (t == 0) {
        out[0] = (float)(l1[0] / (double)N_CELLS);
        out[1] = (float)(-l2[0] / (double)N_CELLS);
    }
}

extern "C" void kernel_launch(void* const* d_in, const int* in_sizes, int n_in,
                              void* d_out, int out_size, void* d_ws, size_t ws_size,
                              hipStream_t stream) {
    const float* X   = (const float*)d_in[0];
    const float* Mu  = (const float*)d_in[1];
    const float* Var = (const float*)d_in[2];
    const float* W   = (const float*)d_in[3];
    const float* S   = (const float*)d_in[4];
    const int*   ei  = (const int*)d_in[5];
    const float* wl  = (const float*)d_in[6];
    const float* bl  = (const float*)d_in[7];
    const float* wr  = (const float*)d_in[8];
    const float* br  = (const float*)d_in[9];
    const float* att = (const float*)d_in[10];
    float* out = (float*)d_out;
    char*  ws  = (char*)d_ws;

    ushort*   Bf    = (ushort*)(ws + OFF_BF);
    float*    t3    = (float*)(ws + OFF_T3);
    float*    glr   = (float*)(ws + OFF_GLR);
    float*    score = (float*)(ws + OFF_SCORE);
    unsigned* mseg  = (unsigned*)(ws + OFF_MSEG);
    float*    denom = (float*)(ws + OFF_DENOM);
    float*    numer = (float*)(ws + OFF_NUMER);
    float*    llp   = (float*)(ws + OFF_LLP);
    float*    cep   = (float*)(ws + OFF_CEP);
    float*    P     = out + 2;

    hipMemsetAsync(ws + ZERO_BEG, 0, ZERO_BYTES, stream);

    k_prepB  <<<288, 256, 0, stream>>>(Var, Mu, wl, wr, Bf);
    k_t3     <<<N_CLASSES, 64, 0, stream>>>(Var, Mu, t3);
    k_softmax<<<(N_CELLS * 64 + 255) / 256, 256, 0, stream>>>(W, P);
    k_fused  <<<NB_FUSED, 256, 0, stream>>>(X, S, P, Bf, t3, bl, br, glr, llp);
    k_score  <<<(N_EDGES + 255) / 256, 256, 0, stream>>>(ei, glr, att, score, mseg);
    k_edge2  <<<(N_EDGES * 16 + 255) / 256, 256, 0, stream>>>(ei, score, mseg, P, denom, numer);
    k_ce     <<<NB_CE, 256, 0, stream>>>(denom, numer, cep);
    k_reduce <<<1, 256, 0, stream>>>(llp, cep, out);
}

// Round 5
// 206.067 us; speedup vs baseline: 3.9064x; 1.1585x over previous
//
#include <hip/hip_runtime.h>
#include <math.h>

#define N_CELLS   100000
#define N_CLASSES 50
#define N_GENES   500
#define N_EDGES   600000
#define HID       8
#define NKT       8    // K tiles of 64 floats (512 padded)
#define NB_FUSED  1563 // (N_CELLS+63)/64
#define NB_CE     391  // (N_CELLS+255)/256

typedef __attribute__((ext_vector_type(4))) float f32x4;
typedef __attribute__((ext_vector_type(8))) short bf16x8;

// ---- workspace layout (bytes) ----
// Bf: k-tile-major main region [8 kt][16 chunk][64 lane][8 bf16] = 131072 B,
//     then glr tile [16 s][64 lane][8 bf16] = 16384 B
static const size_t OFF_BF    = 0;                 // 147456 B bf16 B-fragments
static const size_t OFF_T3    = 147456;            // 64 f32
static const size_t OFF_GLR   = 147712;            // [N][16] f32, 6.4 MB
static const size_t OFF_SCORE = 6547712;           // [E] f32, 2.4 MB
static const size_t OFF_MSEG  = 8947712;           // [N] u32 (mapped max)
static const size_t OFF_DENOM = 9347712;           // [N] f32
static const size_t OFF_NUMER = 9747712;           // [N] f32
static const size_t OFF_LLP   = 10147712;          // [NB_FUSED] f32 partials
static const size_t OFF_CEP   = 10153968;          // [NB_CE] f32 partials
static const size_t ZERO_BEG  = OFF_MSEG;
static const size_t ZERO_BYTES= 10147712 - 8947712;   // mseg+denom+numer only

__device__ __forceinline__ ushort f2bf(float f) {
    union { float f; unsigned u; } v; v.f = f;
    unsigned r = v.u + 0x7fffu + ((v.u >> 16) & 1u);   // RNE
    return (ushort)(r >> 16);
}

__device__ __forceinline__ unsigned cvt_pk_bf16(float lo, float hi) {
    unsigned r;
    asm("v_cvt_pk_bf16_f32 %0, %1, %2" : "=v"(r) : "v"(lo), "v"(hi));
    return r;
}

__device__ __forceinline__ void gload16(const void* g, void* l) {
    __builtin_amdgcn_global_load_lds(
        (const __attribute__((address_space(1))) unsigned int*)g,
        (__attribute__((address_space(3))) unsigned int*)l,
        16, 0, 0);
}

// ---------- prep: B fragments, k-tile-major for LDS staging ----------
__global__ __launch_bounds__(256) void k_prepB(const float* __restrict__ Var,
                                               const float* __restrict__ Mu,
                                               const float* __restrict__ wl,
                                               const float* __restrict__ wr,
                                               ushort* __restrict__ Bf) {
    int id = blockIdx.x * 256 + threadIdx.x;           // 0..73727 exact
    float v = 0.f;
    if (id < 65536) {
        // main region: [kt][j=t*2+ss][lane][e]
        int e    = id & 7;
        int lane = (id >> 3) & 63;
        int j    = (id >> 9) & 15;
        int kt   = id >> 13;              // 0..7
        int t    = j >> 1, ss = j & 1;
        int s    = kt * 2 + ss;
        int k    = s * 32 + ((lane >> 4) << 3) + e;
        int c    = (t & 3) * 16 + (lane & 15);
        if (k < N_GENES && c < N_CLASSES)
            v = (t < 4) ? 1.0f / Var[c * N_GENES + k]
                        : Mu[c * N_GENES + k] / Var[c * N_GENES + k];
    } else {
        // glr tile: [s][lane][e]
        int rem  = id - 65536;
        int e    = rem & 7;
        int lane = (rem >> 3) & 63;
        int s    = rem >> 9;              // 0..15
        int k    = s * 32 + ((lane >> 4) << 3) + e;
        int h    = lane & 15;
        if (k < N_GENES)
            v = (h < HID) ? wl[h * N_GENES + k] : wr[(h - HID) * N_GENES + k];
    }
    Bf[id] = f2bf(v);
}

// ---------- t3: block per class, wave-parallel over genes ----------
__global__ void k_t3(const float* __restrict__ Var, const float* __restrict__ Mu,
                     float* __restrict__ t3) {
    int c = blockIdx.x;
    int lane = threadIdx.x;
    float s = 0.f;
    for (int g = lane; g < N_GENES; g += 64) {
        float m = Mu[c * N_GENES + g];
        s += m * m / Var[c * N_GENES + g];
    }
    #pragma unroll
    for (int off = 32; off; off >>= 1) s += __shfl_xor(s, off);
    if (lane == 0) t3[c] = s;
}

// ---------- row softmax ----------
__global__ __launch_bounds__(256) void k_softmax(const float* __restrict__ W,
                                                 float* __restrict__ P) {
    int wid  = (blockIdx.x * 256 + threadIdx.x) >> 6;
    int lane = threadIdx.x & 63;
    if (wid >= N_CELLS) return;
    float w = (lane < N_CLASSES) ? W[(size_t)wid * N_CLASSES + lane] : -__builtin_inff();
    float m = w;
    #pragma unroll
    for (int off = 32; off; off >>= 1) m = fmaxf(m, __shfl_xor(m, off));
    float e = (lane < N_CLASSES) ? expf(w - m) : 0.f;
    float s = e;
    #pragma unroll
    for (int off = 32; off; off >>= 1) s += __shfl_xor(s, off);
    if (lane < N_CLASSES) P[(size_t)wid * N_CLASSES + lane] = e / s;
}

// ---------- fused MFMA: Gaussian LL + gl/gr projection ----------
// A (64x64 f32) and B (16KB class-tiles) both staged via global_load_lds,
// double-buffered, one barrier per K-tile. B reads are ds_read_b128.
__global__ __launch_bounds__(256, 1) void k_fused(const float* __restrict__ X,
                                                  const float* __restrict__ S,
                                                  const float* __restrict__ P,
                                                  const ushort* __restrict__ Bf,
                                                  const float* __restrict__ t3,
                                                  const float* __restrict__ bl,
                                                  const float* __restrict__ br,
                                                  float* __restrict__ glr,
                                                  float* __restrict__ llp) {
    __shared__ float  ldsA[2][4][16][16][4];   // 32 KB
    __shared__ ushort ldsB[2][16][64][8];      // 32 KB
    int tid  = threadIdx.x;
    int lane = tid & 63;
    int wv   = tid >> 6;
    int lhi  = lane >> 4;
    int slot = lane & 15;
    int rbase = blockIdx.x * 64;
    const char* Xc  = (const char*)X;
    const char* Bfc = (const char*)Bf;
    const bf16x8* Bg8 = (const bf16x8*)(Bf + 65536);   // glr tile, global

    int arow = rbase + wv * 16 + (lane & 15);
    if (arow > N_CELLS - 1) arow = N_CELLS - 1;
    float sv  = S[arow];
    float m2s = -2.0f * sv;

    const f32x4 zz = {0.f, 0.f, 0.f, 0.f};
    f32x4 acc1[4], acc2[4], acc3;
    #pragma unroll
    for (int ct = 0; ct < 4; ++ct) { acc1[ct] = zz; acc2[ct] = zz; }
    acc3 = zz;

    // ---- stage kt=0 into buf 0 ----
    #pragma unroll
    for (int i = 0; i < 4; ++i) {
        int rloc = i * 4 + lhi;
        int row  = rbase + wv * 16 + rloc; if (row > N_CELLS - 1) row = N_CELLS - 1;
        int gi   = slot ^ (rloc & 7); if (gi > 124) gi = 124;
        gload16(Xc + (size_t)row * 2000 + (size_t)gi * 16, &ldsA[0][wv][i * 4][0][0]);
    }
    #pragma unroll
    for (int i = 0; i < 4; ++i) {
        int j = wv * 4 + i;
        gload16(Bfc + (size_t)j * 1024 + (size_t)lane * 16, &ldsB[0][j][0][0]);
    }

    int cur = 0;
    for (int kt = 0; kt < NKT; ++kt) {
        __syncthreads();
        if (kt < NKT - 1) {
            int nxt = cur ^ 1;
            #pragma unroll
            for (int i = 0; i < 4; ++i) {
                int rloc = i * 4 + lhi;
                int row  = rbase + wv * 16 + rloc; if (row > N_CELLS - 1) row = N_CELLS - 1;
                int gi   = (kt + 1) * 16 + (slot ^ (rloc & 7)); if (gi > 124) gi = 124;
                gload16(Xc + (size_t)row * 2000 + (size_t)gi * 16, &ldsA[nxt][wv][i * 4][0][0]);
            }
            #pragma unroll
            for (int i = 0; i < 4; ++i) {
                int j = wv * 4 + i;
                gload16(Bfc + (size_t)(kt + 1) * 16384 + (size_t)j * 1024 + (size_t)lane * 16,
                        &ldsB[nxt][j][0][0]);
            }
        }
        const bf16x8* BL = (const bf16x8*)&ldsB[cur][0][0][0];
        #pragma unroll
        for (int ks = 0; ks < 2; ++ks) {
            int rloc = lane & 15, key = rloc & 7;
            int g8   = ks * 8 + lhi * 2;
            f32x4 xa = *(const f32x4*)&ldsA[cur][wv][rloc][g8 ^ key][0];
            f32x4 xb = *(const f32x4*)&ldsA[cur][wv][rloc][(g8 + 1) ^ key][0];
            union { bf16x8 v; unsigned u[4]; } a1, a2;
            a1.u[0] = cvt_pk_bf16(xa[0] * xa[0], xa[1] * xa[1]);
            a1.u[1] = cvt_pk_bf16(xa[2] * xa[2], xa[3] * xa[3]);
            a1.u[2] = cvt_pk_bf16(xb[0] * xb[0], xb[1] * xb[1]);
            a1.u[3] = cvt_pk_bf16(xb[2] * xb[2], xb[3] * xb[3]);
            a2.u[0] = cvt_pk_bf16(m2s * xa[0], m2s * xa[1]);
            a2.u[1] = cvt_pk_bf16(m2s * xa[2], m2s * xa[3]);
            a2.u[2] = cvt_pk_bf16(m2s * xb[0], m2s * xb[1]);
            a2.u[3] = cvt_pk_bf16(m2s * xb[2], m2s * xb[3]);
            bf16x8 bg = Bg8[(size_t)(kt * 2 + ks) * 64 + lane];
            #pragma unroll
            for (int ct = 0; ct < 4; ++ct)
                acc1[ct] = __builtin_amdgcn_mfma_f32_16x16x32_bf16(a1.v, BL[(ct * 2 + ks) * 64 + lane], acc1[ct], 0, 0, 0);
            #pragma unroll
            for (int ct = 0; ct < 4; ++ct)
                acc2[ct] = __builtin_amdgcn_mfma_f32_16x16x32_bf16(a2.v, BL[((4 + ct) * 2 + ks) * 64 + lane], acc2[ct], 0, 0, 0);
            acc3 = __builtin_amdgcn_mfma_f32_16x16x32_bf16(a2.v, bg, acc3, 0, 0, 0);
        }
        cur ^= 1;
    }

    // ---- epilogue ----
    int col = lane & 15;
    int rg  = lane >> 4;
    float bias = (col < HID) ? bl[col] : br[col - HID];
    float part = 0.f;
    #pragma unroll
    for (int r = 0; r < 4; ++r) {
        int row = rbase + wv * 16 + rg * 4 + r;
        if (row < N_CELLS) {
            float s2 = S[row];
            glr[(size_t)row * 16 + col] = acc3[r] / (-2.0f * s2) + bias;
            float ss = s2 * s2;
            #pragma unroll
            for (int ct = 0; ct < 4; ++ct) {
                int c = ct * 16 + col;
                if (c < N_CLASSES) {
                    float F = -0.5f * (acc1[ct][r] + acc2[ct][r] + ss * t3[c]);
                    part = fmaf(P[(size_t)row * N_CLASSES + c], F, part);
                }
            }
        }
    }
    #pragma unroll
    for (int off = 32; off; off >>= 1) part += __shfl_xor(part, off);
    float* wsum = (float*)&ldsA[0][0][0][0][0];   // reuse LDS (safe: all compute done)
    __syncthreads();
    if (lane == 0) wsum[wv] = part;
    __syncthreads();
    if (tid == 0) llp[blockIdx.x] = wsum[0] + wsum[1] + wsum[2] + wsum[3];
}

// ---------- edge scores + segment max ----------
__device__ __forceinline__ unsigned map_f32(float f) {
    int s = __float_as_int(f);
    return (s < 0) ? ~(unsigned)s : ((unsigned)s | 0x80000000u);
}
__device__ __forceinline__ float unmap_f32(unsigned u) {
    return (u & 0x80000000u) ? __int_as_float((int)(u & 0x7fffffffu))
                             : __int_as_float((int)~u);
}

__global__ __launch_bounds__(256) void k_score(const int* __restrict__ ei,
                                               const float* __restrict__ glr,
                                               const float* __restrict__ att,
                                               float* __restrict__ score,
                                               unsigned* __restrict__ mseg) {
    int e = blockIdx.x * 256 + threadIdx.x;
    if (e >= N_EDGES) return;
    int src = ei[e], dst = ei[N_EDGES + e];
    const float4* a = (const float4*)(glr + (size_t)src * 16);       // gl
    const float4* b = (const float4*)(glr + (size_t)dst * 16 + 8);   // gr
    float4 g0 = a[0], g1 = a[1], h0 = b[0], h1 = b[1];
    const float4* at = (const float4*)att;
    float4 a0 = at[0], a1 = at[1];
    float v, s = 0.f;
    v = g0.x + h0.x; v = v > 0.f ? v : 0.2f * v; s = fmaf(a0.x, v, s);
    v = g0.y + h0.y; v = v > 0.f ? v : 0.2f * v; s = fmaf(a0.y, v, s);
    v = g0.z + h0.z; v = v > 0.f ? v : 0.2f * v; s = fmaf(a0.z, v, s);
    v = g0.w + h0.w; v = v > 0.f ? v : 0.2f * v; s = fmaf(a0.w, v, s);
    v = g1.x + h1.x; v = v > 0.f ? v : 0.2f * v; s = fmaf(a1.x, v, s);
    v = g1.y + h1.y; v = v > 0.f ? v : 0.2f * v; s = fmaf(a1.y, v, s);
    v = g1.z + h1.z; v = v > 0.f ? v : 0.2f * v; s = fmaf(a1.z, v, s);
    v = g1.w + h1.w; v = v > 0.f ? v : 0.2f * v; s = fmaf(a1.w, v, s);
    score[e] = s;
    atomicMax(mseg + dst, map_f32(s));
}

// ---------- fused exp/segment-sum/CE gather: 16 lanes per edge ----------
__global__ __launch_bounds__(256) void k_edge2(const int* __restrict__ ei,
                                               const float* __restrict__ score,
                                               const unsigned* __restrict__ mseg,
                                               const float* __restrict__ P,
                                               float* __restrict__ denom,
                                               float* __restrict__ numer) {
    int t = blockIdx.x * 256 + threadIdx.x;
    int e = t >> 4;
    int q = t & 15;
    if (e >= N_EDGES) return;
    int src = ei[e], dst = ei[N_EDGES + e];
    float ex = expf(score[e] - unmap_f32(mseg[dst]));
    const float* Ps = P + (size_t)src * N_CLASSES;
    const float* Pd = P + (size_t)dst * N_CLASSES;
    float v = Ps[q]      * logf(Pd[q]      + 1e-8f)
            + Ps[q + 16] * logf(Pd[q + 16] + 1e-8f)
            + Ps[q + 32] * logf(Pd[q + 32] + 1e-8f);
    if (q < 2) v += Ps[q + 48] * logf(Pd[q + 48] + 1e-8f);
    v += __shfl_xor(v, 8); v += __shfl_xor(v, 4);
    v += __shfl_xor(v, 2); v += __shfl_xor(v, 1);
    if (q == 0) {
        atomicAdd(denom + dst, ex);
        atomicAdd(numer + dst, ex * v);
    }
}

// ---------- CE node reduce -> per-block partial ----------
__global__ __launch_bounds__(256) void k_ce(const float* __restrict__ denom,
                                            const float* __restrict__ numer,
                                            float* __restrict__ cep) {
    __shared__ float wsum[4];
    int n = blockIdx.x * 256 + threadIdx.x;
    float v = 0.f;
    if (n < N_CELLS) {
        float d = denom[n];
        v = (d > 0.f) ? numer[n] / d : 0.f;
    }
    #pragma unroll
    for (int off = 32; off; off >>= 1) v += __shfl_xor(v, off);
    if ((threadIdx.x & 63) == 0) wsum[threadIdx.x >> 6] = v;
    __syncthreads();
    if (threadIdx.x == 0) cep[blockIdx.x] = wsum[0] + wsum[1] + wsum[2] + wsum[3];
}

// ---------- final: reduce partials in f64, write scalars ----------
__global__ __launch_bounds__(256) void k_reduce(const float* __restrict__ llp,
                                                const float* __restrict__ cep,
                                                float* __restrict__ out) {
    __shared__ double l1[256], l2[256];
    int t = threadIdx.x;
    double s1 = 0.0, s2 = 0.0;
    for (int i = t; i < NB_FUSED; i += 256) s1 += (double)llp[i];
    for (int i = t; i < NB_CE; i += 256) s2 += (double)cep[i];
    l1[t] = s1; l2[t] = s2;
    __syncthreads();
    for (int off = 128; off; off >>= 1) {
        if (t < off) { l1[t] += l1[t + off]; l2[t] += l2[t + off]; }
        __syncthreads();
    }
    if (t == 0) {
        out[0] = (float)(l1[0] / (double)N_CELLS);
        out[1] = (float)(-l2[0] / (double)N_CELLS);
    }
}

extern "C" void kernel_launch(void* const* d_in, const int* in_sizes, int n_in,
                              void* d_out, int out_size, void* d_ws, size_t ws_size,
                              hipStream_t stream) {
    const float* X   = (const float*)d_in[0];
    const float* Mu  = (const float*)d_in[1];
    const float* Var = (const float*)d_in[2];
    const float* W   = (const float*)d_in[3];
    const float* S   = (const float*)d_in[4];
    const int*   ei  = (const int*)d_in[5];
    const float* wl  = (const float*)d_in[6];
    const float* bl  = (const float*)d_in[7];
    const float* wr  = (const float*)d_in[8];
    const float* br  = (const float*)d_in[9];
    const float* att = (const float*)d_in[10];
    float* out = (float*)d_out;
    char*  ws  = (char*)d_ws;

    ushort*   Bf    = (ushort*)(ws + OFF_BF);
    float*    t3    = (float*)(ws + OFF_T3);
    float*    glr   = (float*)(ws + OFF_GLR);
    float*    score = (float*)(ws + OFF_SCORE);
    unsigned* mseg  = (unsigned*)(ws + OFF_MSEG);
    float*    denom = (float*)(ws + OFF_DENOM);
    float*    numer = (float*)(ws + OFF_NUMER);
    float*    llp   = (float*)(ws + OFF_LLP);
    float*    cep   = (float*)(ws + OFF_CEP);
    float*    P     = out + 2;

    hipMemsetAsync(ws + ZERO_BEG, 0, ZERO_BYTES, stream);

    k_prepB  <<<288, 256, 0, stream>>>(Var, Mu, wl, wr, Bf);
    k_t3     <<<N_CLASSES, 64, 0, stream>>>(Var, Mu, t3);
    k_softmax<<<(N_CELLS * 64 + 255) / 256, 256, 0, stream>>>(W, P);
    k_fused  <<<NB_FUSED, 256, 0, stream>>>(X, S, P, Bf, t3, bl, br, glr, llp);
    k_score  <<<(N_EDGES + 255) / 256, 256, 0, stream>>>(ei, glr, att, score, mseg);
    k_edge2  <<<(N_EDGES * 16 + 255) / 256, 256, 0, stream>>>(ei, score, mseg, P, denom, numer);
    k_ce     <<<NB_CE, 256, 0, stream>>>(denom, numer, cep);
    k_reduce <<<1, 256, 0, stream>>>(llp, cep, out);
}

// Round 6
// 196.331 us; speedup vs baseline: 4.1002x; 1.0496x over previous
//
#include <hip/hip_runtime.h>
#include <math.h>

#define N_CELLS   100000
#define N_CLASSES 50
#define N_GENES   500
#define N_EDGES   600000
#define HID       8
#define NKT       8    // K tiles of 64 floats (512 padded)
#define NB_FUSED  782  // ceil(N_CELLS/128)
#define NB_CE     391  // (N_CELLS+255)/256

typedef __attribute__((ext_vector_type(4))) float f32x4;
typedef __attribute__((ext_vector_type(8))) short bf16x8;

// ---- workspace layout (bytes) ----
// Bf: k-tile-major main region [8 kt][16 chunk][64 lane][8 bf16] = 131072 B,
//     then glr tile [16 s][64 lane][8 bf16] = 16384 B
static const size_t OFF_BF    = 0;                 // 147456 B bf16 B-fragments
static const size_t OFF_T3    = 147456;            // 64 f32
static const size_t OFF_GLR   = 147712;            // [N][16] f32, 6.4 MB
static const size_t OFF_SCORE = 6547712;           // [E] f32, 2.4 MB
static const size_t OFF_MSEG  = 8947712;           // [N] u32 (mapped max)
static const size_t OFF_DENOM = 9347712;           // [N] f32
static const size_t OFF_NUMER = 9747712;           // [N] f32
static const size_t OFF_LLP   = 10147712;          // [NB_FUSED] f32 partials
static const size_t OFF_CEP   = 10153968;          // [NB_CE] f32 partials
static const size_t ZERO_BEG  = OFF_MSEG;
static const size_t ZERO_BYTES= 10147712 - 8947712;   // mseg+denom+numer only

__device__ __forceinline__ ushort f2bf(float f) {
    union { float f; unsigned u; } v; v.f = f;
    unsigned r = v.u + 0x7fffu + ((v.u >> 16) & 1u);   // RNE
    return (ushort)(r >> 16);
}

__device__ __forceinline__ unsigned cvt_pk_bf16(float lo, float hi) {
    unsigned r;
    asm("v_cvt_pk_bf16_f32 %0, %1, %2" : "=v"(r) : "v"(lo), "v"(hi));
    return r;
}

__device__ __forceinline__ void gload16(const void* g, void* l) {
    __builtin_amdgcn_global_load_lds(
        (const __attribute__((address_space(1))) unsigned int*)g,
        (__attribute__((address_space(3))) unsigned int*)l,
        16, 0, 0);
}

// ---------- prep: B fragments, k-tile-major for LDS staging ----------
__global__ __launch_bounds__(256) void k_prepB(const float* __restrict__ Var,
                                               const float* __restrict__ Mu,
                                               const float* __restrict__ wl,
                                               const float* __restrict__ wr,
                                               ushort* __restrict__ Bf) {
    int id = blockIdx.x * 256 + threadIdx.x;           // 0..73727 exact
    float v = 0.f;
    if (id < 65536) {
        // main region: [kt][j=t*2+ss][lane][e]
        int e    = id & 7;
        int lane = (id >> 3) & 63;
        int j    = (id >> 9) & 15;
        int kt   = id >> 13;              // 0..7
        int t    = j >> 1, ss = j & 1;
        int s    = kt * 2 + ss;
        int k    = s * 32 + ((lane >> 4) << 3) + e;
        int c    = (t & 3) * 16 + (lane & 15);
        if (k < N_GENES && c < N_CLASSES)
            v = (t < 4) ? 1.0f / Var[c * N_GENES + k]
                        : Mu[c * N_GENES + k] / Var[c * N_GENES + k];
    } else {
        // glr tile: [s][lane][e]
        int rem  = id - 65536;
        int e    = rem & 7;
        int lane = (rem >> 3) & 63;
        int s    = rem >> 9;              // 0..15
        int k    = s * 32 + ((lane >> 4) << 3) + e;
        int h    = lane & 15;
        if (k < N_GENES)
            v = (h < HID) ? wl[h * N_GENES + k] : wr[(h - HID) * N_GENES + k];
    }
    Bf[id] = f2bf(v);
}

// ---------- t3: block per class, wave-parallel over genes ----------
__global__ void k_t3(const float* __restrict__ Var, const float* __restrict__ Mu,
                     float* __restrict__ t3) {
    int c = blockIdx.x;
    int lane = threadIdx.x;
    float s = 0.f;
    for (int g = lane; g < N_GENES; g += 64) {
        float m = Mu[c * N_GENES + g];
        s += m * m / Var[c * N_GENES + g];
    }
    #pragma unroll
    for (int off = 32; off; off >>= 1) s += __shfl_xor(s, off);
    if (lane == 0) t3[c] = s;
}

// ---------- row softmax ----------
__global__ __launch_bounds__(256) void k_softmax(const float* __restrict__ W,
                                                 float* __restrict__ P) {
    int wid  = (blockIdx.x * 256 + threadIdx.x) >> 6;
    int lane = threadIdx.x & 63;
    if (wid >= N_CELLS) return;
    float w = (lane < N_CLASSES) ? W[(size_t)wid * N_CLASSES + lane] : -__builtin_inff();
    float m = w;
    #pragma unroll
    for (int off = 32; off; off >>= 1) m = fmaxf(m, __shfl_xor(m, off));
    float e = (lane < N_CLASSES) ? expf(w - m) : 0.f;
    float s = e;
    #pragma unroll
    for (int off = 32; off; off >>= 1) s += __shfl_xor(s, off);
    if (lane < N_CLASSES) P[(size_t)wid * N_CLASSES + lane] = e / s;
}

// ---------- fused MFMA: Gaussian LL + gl/gr projection ----------
// 32 rows/wave (128/block): each B ds_read feeds TWO row-group MFMAs.
// Single-buffered A(32KB)+B(16KB) LDS -> 3 blocks/CU; 2 barriers/K-tile.
__global__ __launch_bounds__(256, 3) void k_fused(const float* __restrict__ X,
                                                  const float* __restrict__ S,
                                                  const float* __restrict__ P,
                                                  const ushort* __restrict__ Bf,
                                                  const float* __restrict__ t3,
                                                  const float* __restrict__ bl,
                                                  const float* __restrict__ br,
                                                  float* __restrict__ glr,
                                                  float* __restrict__ llp) {
    __shared__ float  ldsA[4][32][16][4];   // [wave][row][slot][4 f32] = 32 KB
    __shared__ ushort ldsB[16][64][8];      // 16 KB
    __shared__ float  wsum[4];
    int tid  = threadIdx.x;
    int lane = tid & 63;
    int wv   = tid >> 6;
    int lhi  = lane >> 4;
    int slot = lane & 15;
    int rbase = blockIdx.x * 128 + wv * 32;   // this wave's 32 rows
    const char* Xc  = (const char*)X;
    const char* Bfc = (const char*)Bf;
    const bf16x8* Bg8 = (const bf16x8*)(Bf + 65536);   // glr tile, global

    int ar0 = rbase + slot;      if (ar0 > N_CELLS - 1) ar0 = N_CELLS - 1;
    int ar1 = rbase + 16 + slot; if (ar1 > N_CELLS - 1) ar1 = N_CELLS - 1;
    float m2s0 = -2.0f * S[ar0];
    float m2s1 = -2.0f * S[ar1];

    const f32x4 zz = {0.f, 0.f, 0.f, 0.f};
    f32x4 acc1[2][4], acc2[2][4], acc3[2];
    #pragma unroll
    for (int g = 0; g < 2; ++g) {
        #pragma unroll
        for (int ct = 0; ct < 4; ++ct) { acc1[g][ct] = zz; acc2[g][ct] = zz; }
        acc3[g] = zz;
    }

    for (int kt = 0; kt < NKT; ++kt) {
        __syncthreads();   // previous tile's compute done (safe to overwrite)
        // ---- stage A: 8 rounds of 1KB/wave, XOR-swizzled global source ----
        #pragma unroll
        for (int i = 0; i < 8; ++i) {
            int rloc = i * 4 + lhi;
            int row  = rbase + rloc; if (row > N_CELLS - 1) row = N_CELLS - 1;
            int gi   = kt * 16 + (slot ^ (rloc & 7)); if (gi > 124) gi = 124;
            gload16(Xc + (size_t)row * 2000 + (size_t)gi * 16, &ldsA[wv][i * 4][0][0]);
        }
        // ---- stage B: 4 chunks per wave, linear ----
        #pragma unroll
        for (int i = 0; i < 4; ++i) {
            int j = wv * 4 + i;
            gload16(Bfc + (size_t)kt * 16384 + (size_t)j * 1024 + (size_t)lane * 16,
                    &ldsB[j][0][0]);
        }
        __syncthreads();   // drains vmcnt(0): tile ready
        const bf16x8* BL = (const bf16x8*)&ldsB[0][0][0];
        #pragma unroll
        for (int ks = 0; ks < 2; ++ks) {
            int key = lane & 7;
            int c0  = ks * 8 + lhi * 2;
            f32x4 xa0 = *(const f32x4*)&ldsA[wv][slot][c0 ^ key][0];
            f32x4 xb0 = *(const f32x4*)&ldsA[wv][slot][(c0 + 1) ^ key][0];
            f32x4 xa1 = *(const f32x4*)&ldsA[wv][16 + slot][c0 ^ key][0];
            f32x4 xb1 = *(const f32x4*)&ldsA[wv][16 + slot][(c0 + 1) ^ key][0];
            union { bf16x8 v; unsigned u[4]; } a1g0, a2g0, a1g1, a2g1;
            a1g0.u[0] = cvt_pk_bf16(xa0[0] * xa0[0], xa0[1] * xa0[1]);
            a1g0.u[1] = cvt_pk_bf16(xa0[2] * xa0[2], xa0[3] * xa0[3]);
            a1g0.u[2] = cvt_pk_bf16(xb0[0] * xb0[0], xb0[1] * xb0[1]);
            a1g0.u[3] = cvt_pk_bf16(xb0[2] * xb0[2], xb0[3] * xb0[3]);
            a2g0.u[0] = cvt_pk_bf16(m2s0 * xa0[0], m2s0 * xa0[1]);
            a2g0.u[1] = cvt_pk_bf16(m2s0 * xa0[2], m2s0 * xa0[3]);
            a2g0.u[2] = cvt_pk_bf16(m2s0 * xb0[0], m2s0 * xb0[1]);
            a2g0.u[3] = cvt_pk_bf16(m2s0 * xb0[2], m2s0 * xb0[3]);
            a1g1.u[0] = cvt_pk_bf16(xa1[0] * xa1[0], xa1[1] * xa1[1]);
            a1g1.u[1] = cvt_pk_bf16(xa1[2] * xa1[2], xa1[3] * xa1[3]);
            a1g1.u[2] = cvt_pk_bf16(xb1[0] * xb1[0], xb1[1] * xb1[1]);
            a1g1.u[3] = cvt_pk_bf16(xb1[2] * xb1[2], xb1[3] * xb1[3]);
            a2g1.u[0] = cvt_pk_bf16(m2s1 * xa1[0], m2s1 * xa1[1]);
            a2g1.u[1] = cvt_pk_bf16(m2s1 * xa1[2], m2s1 * xa1[3]);
            a2g1.u[2] = cvt_pk_bf16(m2s1 * xb1[0], m2s1 * xb1[1]);
            a2g1.u[3] = cvt_pk_bf16(m2s1 * xb1[2], m2s1 * xb1[3]);
            bf16x8 bg = Bg8[(size_t)(kt * 2 + ks) * 64 + lane];
            #pragma unroll
            for (int ct = 0; ct < 4; ++ct) {
                bf16x8 b = BL[(ct * 2 + ks) * 64 + lane];
                acc1[0][ct] = __builtin_amdgcn_mfma_f32_16x16x32_bf16(a1g0.v, b, acc1[0][ct], 0, 0, 0);
                acc1[1][ct] = __builtin_amdgcn_mfma_f32_16x16x32_bf16(a1g1.v, b, acc1[1][ct], 0, 0, 0);
            }
            #pragma unroll
            for (int ct = 0; ct < 4; ++ct) {
                bf16x8 b = BL[((4 + ct) * 2 + ks) * 64 + lane];
                acc2[0][ct] = __builtin_amdgcn_mfma_f32_16x16x32_bf16(a2g0.v, b, acc2[0][ct], 0, 0, 0);
                acc2[1][ct] = __builtin_amdgcn_mfma_f32_16x16x32_bf16(a2g1.v, b, acc2[1][ct], 0, 0, 0);
            }
            acc3[0] = __builtin_amdgcn_mfma_f32_16x16x32_bf16(a2g0.v, bg, acc3[0], 0, 0, 0);
            acc3[1] = __builtin_amdgcn_mfma_f32_16x16x32_bf16(a2g1.v, bg, acc3[1], 0, 0, 0);
        }
    }

    // ---- epilogue: C/D layout col=lane&15, row=(lane>>4)*4+reg (per group) ----
    int col = lane & 15;
    int rg  = lane >> 4;
    float bias = (col < HID) ? bl[col] : br[col - HID];
    float part = 0.f;
    #pragma unroll
    for (int g = 0; g < 2; ++g) {
        #pragma unroll
        for (int r = 0; r < 4; ++r) {
            int row = rbase + g * 16 + rg * 4 + r;
            if (row < N_CELLS) {
                float s2 = S[row];
                glr[(size_t)row * 16 + col] = acc3[g][r] / (-2.0f * s2) + bias;
                float ss = s2 * s2;
                #pragma unroll
                for (int ct = 0; ct < 4; ++ct) {
                    int c = ct * 16 + col;
                    if (c < N_CLASSES) {
                        float F = -0.5f * (acc1[g][ct][r] + acc2[g][ct][r] + ss * t3[c]);
                        part = fmaf(P[(size_t)row * N_CLASSES + c], F, part);
                    }
                }
            }
        }
    }
    #pragma unroll
    for (int off = 32; off; off >>= 1) part += __shfl_xor(part, off);
    __syncthreads();
    if (lane == 0) wsum[wv] = part;
    __syncthreads();
    if (tid == 0) llp[blockIdx.x] = wsum[0] + wsum[1] + wsum[2] + wsum[3];
}

// ---------- edge scores + segment max ----------
__device__ __forceinline__ unsigned map_f32(float f) {
    int s = __float_as_int(f);
    return (s < 0) ? ~(unsigned)s : ((unsigned)s | 0x80000000u);
}
__device__ __forceinline__ float unmap_f32(unsigned u) {
    return (u & 0x80000000u) ? __int_as_float((int)(u & 0x7fffffffu))
                             : __int_as_float((int)~u);
}

__global__ __launch_bounds__(256) void k_score(const int* __restrict__ ei,
                                               const float* __restrict__ glr,
                                               const float* __restrict__ att,
                                               float* __restrict__ score,
                                               unsigned* __restrict__ mseg) {
    int e = blockIdx.x * 256 + threadIdx.x;
    if (e >= N_EDGES) return;
    int src = ei[e], dst = ei[N_EDGES + e];
    const float4* a = (const float4*)(glr + (size_t)src * 16);       // gl
    const float4* b = (const float4*)(glr + (size_t)dst * 16 + 8);   // gr
    float4 g0 = a[0], g1 = a[1], h0 = b[0], h1 = b[1];
    const float4* at = (const float4*)att;
    float4 a0 = at[0], a1 = at[1];
    float v, s = 0.f;
    v = g0.x + h0.x; v = v > 0.f ? v : 0.2f * v; s = fmaf(a0.x, v, s);
    v = g0.y + h0.y; v = v > 0.f ? v : 0.2f * v; s = fmaf(a0.y, v, s);
    v = g0.z + h0.z; v = v > 0.f ? v : 0.2f * v; s = fmaf(a0.z, v, s);
    v = g0.w + h0.w; v = v > 0.f ? v : 0.2f * v; s = fmaf(a0.w, v, s);
    v = g1.x + h1.x; v = v > 0.f ? v : 0.2f * v; s = fmaf(a1.x, v, s);
    v = g1.y + h1.y; v = v > 0.f ? v : 0.2f * v; s = fmaf(a1.y, v, s);
    v = g1.z + h1.z; v = v > 0.f ? v : 0.2f * v; s = fmaf(a1.z, v, s);
    v = g1.w + h1.w; v = v > 0.f ? v : 0.2f * v; s = fmaf(a1.w, v, s);
    score[e] = s;
    atomicMax(mseg + dst, map_f32(s));
}

// ---------- fused exp/segment-sum/CE gather: 16 lanes per edge ----------
__global__ __launch_bounds__(256) void k_edge2(const int* __restrict__ ei,
                                               const float* __restrict__ score,
                                               const unsigned* __restrict__ mseg,
                                               const float* __restrict__ P,
                                               float* __restrict__ denom,
                                               float* __restrict__ numer) {
    int t = blockIdx.x * 256 + threadIdx.x;
    int e = t >> 4;
    int q = t & 15;
    if (e >= N_EDGES) return;
    int src = ei[e], dst = ei[N_EDGES + e];
    float ex = expf(score[e] - unmap_f32(mseg[dst]));
    const float* Ps = P + (size_t)src * N_CLASSES;
    const float* Pd = P + (size_t)dst * N_CLASSES;
    float v = Ps[q]      * logf(Pd[q]      + 1e-8f)
            + Ps[q + 16] * logf(Pd[q + 16] + 1e-8f)
            + Ps[q + 32] * logf(Pd[q + 32] + 1e-8f);
    if (q < 2) v += Ps[q + 48] * logf(Pd[q + 48] + 1e-8f);
    v += __shfl_xor(v, 8); v += __shfl_xor(v, 4);
    v += __shfl_xor(v, 2); v += __shfl_xor(v, 1);
    if (q == 0) {
        atomicAdd(denom + dst, ex);
        atomicAdd(numer + dst, ex * v);
    }
}

// ---------- CE node reduce -> per-block partial ----------
__global__ __launch_bounds__(256) void k_ce(const float* __restrict__ denom,
                                            const float* __restrict__ numer,
                                            float* __restrict__ cep) {
    __shared__ float wsum[4];
    int n = blockIdx.x * 256 + threadIdx.x;
    float v = 0.f;
    if (n < N_CELLS) {
        float d = denom[n];
        v = (d > 0.f) ? numer[n] / d : 0.f;
    }
    #pragma unroll
    for (int off = 32; off; off >>= 1) v += __shfl_xor(v, off);
    if ((threadIdx.x & 63) == 0) wsum[threadIdx.x >> 6] = v;
    __syncthreads();
    if (threadIdx.x == 0) cep[blockIdx.x] = wsum[0] + wsum[1] + wsum[2] + wsum[3];
}

// ---------- final: reduce partials in f64, write scalars ----------
__global__ __launch_bounds__(256) void k_reduce(const float* __restrict__ llp,
                                                const float* __restrict__ cep,
                                                float* __restrict__ out) {
    __shared__ double l1[256], l2[256];
    int t = threadIdx.x;
    double s1 = 0.0, s2 = 0.0;
    for (int i = t; i < NB_FUSED; i += 256) s1 += (double)llp[i];
    for (int i = t; i < NB_CE; i += 256) s2 += (double)cep[i];
    l1[t] = s1; l2[t] = s2;
    __syncthreads();
    for (int off = 128; off; off >>= 1) {
        if (t < off) { l1[t] += l1[t + off]; l2[t] += l2[t + off]; }
        __syncthreads();
    }
    if (t == 0) {
        out[0] = (float)(l1[0] / (double)N_CELLS);
        out[1] = (float)(-l2[0] / (double)N_CELLS);
    }
}

extern "C" void kernel_launch(void* const* d_in, const int* in_sizes, int n_in,
                              void* d_out, int out_size, void* d_ws, size_t ws_size,
                              hipStream_t stream) {
    const float* X   = (const float*)d_in[0];
    const float* Mu  = (const float*)d_in[1];
    const float* Var = (const float*)d_in[2];
    const float* W   = (const float*)d_in[3];
    const float* S   = (const float*)d_in[4];
    const int*   ei  = (const int*)d_in[5];
    const float* wl  = (const float*)d_in[6];
    const float* bl  = (const float*)d_in[7];
    const float* wr  = (const float*)d_in[8];
    const float* br  = (const float*)d_in[9];
    const float* att = (const float*)d_in[10];
    float* out = (float*)d_out;
    char*  ws  = (char*)d_ws;

    ushort*   Bf    = (ushort*)(ws + OFF_BF);
    float*    t3    = (float*)(ws + OFF_T3);
    float*    glr   = (float*)(ws + OFF_GLR);
    float*    score = (float*)(ws + OFF_SCORE);
    unsigned* mseg  = (unsigned*)(ws + OFF_MSEG);
    float*    denom = (float*)(ws + OFF_DENOM);
    float*    numer = (float*)(ws + OFF_NUMER);
    float*    llp   = (float*)(ws + OFF_LLP);
    float*    cep   = (float*)(ws + OFF_CEP);
    float*    P     = out + 2;

    hipMemsetAsync(ws + ZERO_BEG, 0, ZERO_BYTES, stream);

    k_prepB  <<<288, 256, 0, stream>>>(Var, Mu, wl, wr, Bf);
    k_t3     <<<N_CLASSES, 64, 0, stream>>>(Var, Mu, t3);
    k_softmax<<<(N_CELLS * 64 + 255) / 256, 256, 0, stream>>>(W, P);
    k_fused  <<<NB_FUSED, 256, 0, stream>>>(X, S, P, Bf, t3, bl, br, glr, llp);
    k_score  <<<(N_EDGES + 255) / 256, 256, 0, stream>>>(ei, glr, att, score, mseg);
    k_edge2  <<<(N_EDGES * 16 + 255) / 256, 256, 0, stream>>>(ei, score, mseg, P, denom, numer);
    k_ce     <<<NB_CE, 256, 0, stream>>>(denom, numer, cep);
    k_reduce <<<1, 256, 0, stream>>>(llp, cep, out);
}

// Round 7
// 196.173 us; speedup vs baseline: 4.1035x; 1.0008x over previous
//
#include <hip/hip_runtime.h>
#include <math.h>

#define N_CELLS   100000
#define N_CLASSES 50
#define N_GENES   500
#define N_EDGES   600000
#define HID       8
#define NKT       8    // K tiles of 64 floats (512 padded)
#define NB_FUSED  1563 // ceil(N_CELLS/64)
#define NB_CE     391  // (N_CELLS+255)/256

typedef __attribute__((ext_vector_type(4))) float f32x4;
typedef __attribute__((ext_vector_type(8))) short bf16x8;

// ---- workspace layout (bytes) ----
// Bf: k-tile-major main region [8 kt][16 chunk][64 lane][8 bf16] = 131072 B,
//     then glr tile [16 s][64 lane][8 bf16] = 16384 B
static const size_t OFF_BF    = 0;                 // 147456 B bf16 B-fragments
static const size_t OFF_T3    = 147456;            // 64 f32
static const size_t OFF_GLR   = 147712;            // [N][16] f32, 6.4 MB
static const size_t OFF_SCORE = 6547712;           // [E] f32, 2.4 MB
static const size_t OFF_MSEG  = 8947712;           // [N] u32 (mapped max)
static const size_t OFF_DENOM = 9347712;           // [N] f32
static const size_t OFF_NUMER = 9747712;           // [N] f32
static const size_t OFF_LLP   = 10147712;          // [NB_FUSED] f32 partials
static const size_t OFF_CEP   = 10153968;          // [NB_CE] f32 partials
static const size_t ZERO_BEG  = OFF_MSEG;
static const size_t ZERO_BYTES= 10147712 - 8947712;   // mseg+denom+numer only

__device__ __forceinline__ ushort f2bf(float f) {
    union { float f; unsigned u; } v; v.f = f;
    unsigned r = v.u + 0x7fffu + ((v.u >> 16) & 1u);   // RNE
    return (ushort)(r >> 16);
}

__device__ __forceinline__ unsigned cvt_pk_bf16(float lo, float hi) {
    unsigned r;
    asm("v_cvt_pk_bf16_f32 %0, %1, %2" : "=v"(r) : "v"(lo), "v"(hi));
    return r;
}

__device__ __forceinline__ void gload16(const void* g, void* l) {
    __builtin_amdgcn_global_load_lds(
        (const __attribute__((address_space(1))) unsigned int*)g,
        (__attribute__((address_space(3))) unsigned int*)l,
        16, 0, 0);
}

// ---------- prep: B fragments, k-tile-major for LDS staging ----------
__global__ __launch_bounds__(256) void k_prepB(const float* __restrict__ Var,
                                               const float* __restrict__ Mu,
                                               const float* __restrict__ wl,
                                               const float* __restrict__ wr,
                                               ushort* __restrict__ Bf) {
    int id = blockIdx.x * 256 + threadIdx.x;           // 0..73727 exact
    float v = 0.f;
    if (id < 65536) {
        // main region: [kt][j=t*2+ss][lane][e]
        int e    = id & 7;
        int lane = (id >> 3) & 63;
        int j    = (id >> 9) & 15;
        int kt   = id >> 13;              // 0..7
        int t    = j >> 1, ss = j & 1;
        int s    = kt * 2 + ss;
        int k    = s * 32 + ((lane >> 4) << 3) + e;
        int c    = (t & 3) * 16 + (lane & 15);
        if (k < N_GENES && c < N_CLASSES)
            v = (t < 4) ? 1.0f / Var[c * N_GENES + k]
                        : Mu[c * N_GENES + k] / Var[c * N_GENES + k];
    } else {
        // glr tile: [s][lane][e]
        int rem  = id - 65536;
        int e    = rem & 7;
        int lane = (rem >> 3) & 63;
        int s    = rem >> 9;              // 0..15
        int k    = s * 32 + ((lane >> 4) << 3) + e;
        int h    = lane & 15;
        if (k < N_GENES)
            v = (h < HID) ? wl[h * N_GENES + k] : wr[(h - HID) * N_GENES + k];
    }
    Bf[id] = f2bf(v);
}

// ---------- t3: block per class, wave-parallel over genes ----------
__global__ void k_t3(const float* __restrict__ Var, const float* __restrict__ Mu,
                     float* __restrict__ t3) {
    int c = blockIdx.x;
    int lane = threadIdx.x;
    float s = 0.f;
    for (int g = lane; g < N_GENES; g += 64) {
        float m = Mu[c * N_GENES + g];
        s += m * m / Var[c * N_GENES + g];
    }
    #pragma unroll
    for (int off = 32; off; off >>= 1) s += __shfl_xor(s, off);
    if (lane == 0) t3[c] = s;
}

// ---------- row softmax ----------
__global__ __launch_bounds__(256) void k_softmax(const float* __restrict__ W,
                                                 float* __restrict__ P) {
    int wid  = (blockIdx.x * 256 + threadIdx.x) >> 6;
    int lane = threadIdx.x & 63;
    if (wid >= N_CELLS) return;
    float w = (lane < N_CLASSES) ? W[(size_t)wid * N_CLASSES + lane] : -__builtin_inff();
    float m = w;
    #pragma unroll
    for (int off = 32; off; off >>= 1) m = fmaxf(m, __shfl_xor(m, off));
    float e = (lane < N_CLASSES) ? expf(w - m) : 0.f;
    float s = e;
    #pragma unroll
    for (int off = 32; off; off >>= 1) s += __shfl_xor(s, off);
    if (lane < N_CLASSES) P[(size_t)wid * N_CLASSES + lane] = e / s;
}

// ---------- fused MFMA: Gaussian LL + gl/gr projection ----------
// T3/T4-lite: double-buffered A+B LDS, counted s_waitcnt vmcnt(9) (never 0
// in-loop), raw s_barrier x2 per K-tile. Every wave stages exactly 9x1KB.
__global__ __launch_bounds__(256, 2) void k_fused(const float* __restrict__ X,
                                                  const float* __restrict__ S,
                                                  const float* __restrict__ P,
                                                  const ushort* __restrict__ Bf,
                                                  const float* __restrict__ t3,
                                                  const float* __restrict__ bl,
                                                  const float* __restrict__ br,
                                                  float* __restrict__ glr,
                                                  float* __restrict__ llp) {
    __shared__ float  ldsA[2][4][16][16][4];   // [buf][wave][row][slot][4 f32] = 32 KB
    __shared__ ushort ldsB[2][20][64][8];      // [buf][chunk][lane][8] = 40 KB (18 real + 2 pad)
    __shared__ float  wsum[4];
    int tid  = threadIdx.x;
    int lane = tid & 63;
    int wv   = tid >> 6;
    int lhi  = lane >> 4;
    int slot = lane & 15;
    int rbase = blockIdx.x * 64 + wv * 16;    // this wave's 16 rows
    const char* Xc  = (const char*)X;
    const char* Bfc = (const char*)Bf;

    int arow = rbase + slot;
    if (arow > N_CELLS - 1) arow = N_CELLS - 1;
    float m2s = -2.0f * S[arow];

    const f32x4 zz = {0.f, 0.f, 0.f, 0.f};
    f32x4 acc1[4], acc2[4], acc3;
    #pragma unroll
    for (int ct = 0; ct < 4; ++ct) { acc1[ct] = zz; acc2[ct] = zz; }
    acc3 = zz;

    // stage: 4 A-loads (own 16 rows x 64 cols) + 5 B-chunks, all 1KB/lane*16B
#define STAGE(KT, BUF) do {                                                        \
    _Pragma("unroll")                                                              \
    for (int i = 0; i < 4; ++i) {                                                  \
        int rloc = i * 4 + lhi;                                                    \
        int row  = rbase + rloc; if (row > N_CELLS - 1) row = N_CELLS - 1;         \
        int gi   = (KT) * 16 + (slot ^ (rloc & 7)); if (gi > 124) gi = 124;        \
        gload16(Xc + (size_t)row * 2000 + (size_t)gi * 16, &ldsA[BUF][wv][i * 4][0][0]); \
    }                                                                              \
    _Pragma("unroll")                                                              \
    for (int i = 0; i < 5; ++i) {                                                  \
        int j = wv * 5 + i;                                                        \
        size_t src;                                                                \
        if (j < 16)      src = (size_t)(KT) * 16384 + (size_t)j * 1024;            \
        else if (j < 18) src = 131072 + ((size_t)(KT) * 2 + (size_t)(j - 16)) * 1024; \
        else             src = (size_t)(KT) * 16384;                               \
        gload16(Bfc + src + (size_t)lane * 16, &ldsB[BUF][j][0][0]);               \
    }                                                                              \
} while (0)

    STAGE(0, 0);   // prologue: tile 0 -> buf 0 (9 loads in flight)

    #pragma unroll
    for (int kt = 0; kt < NKT; ++kt) {
        const int cur = kt & 1;
        if (kt < NKT - 1) {
            STAGE(kt + 1, cur ^ 1);                          // +9 loads (18 out)
            __builtin_amdgcn_sched_barrier(0);
            asm volatile("s_waitcnt vmcnt(9)" ::: "memory"); // tile kt done, kt+1 in flight
        } else {
            __builtin_amdgcn_sched_barrier(0);
            asm volatile("s_waitcnt vmcnt(0)" ::: "memory");
        }
        __builtin_amdgcn_sched_barrier(0);
        __builtin_amdgcn_s_barrier();                        // all waves' tile-kt loads landed
        __builtin_amdgcn_sched_barrier(0);

        const bf16x8* BL = (const bf16x8*)&ldsB[cur][0][0][0];
        #pragma unroll
        for (int ks = 0; ks < 2; ++ks) {
            int key = slot & 7;
            int c0  = ks * 8 + lhi * 2;
            f32x4 xa = *(const f32x4*)&ldsA[cur][wv][slot][c0 ^ key][0];
            f32x4 xb = *(const f32x4*)&ldsA[cur][wv][slot][(c0 + 1) ^ key][0];
            union { bf16x8 v; unsigned u[4]; } a1, a2;
            a1.u[0] = cvt_pk_bf16(xa[0] * xa[0], xa[1] * xa[1]);
            a1.u[1] = cvt_pk_bf16(xa[2] * xa[2], xa[3] * xa[3]);
            a1.u[2] = cvt_pk_bf16(xb[0] * xb[0], xb[1] * xb[1]);
            a1.u[3] = cvt_pk_bf16(xb[2] * xb[2], xb[3] * xb[3]);
            a2.u[0] = cvt_pk_bf16(m2s * xa[0], m2s * xa[1]);
            a2.u[1] = cvt_pk_bf16(m2s * xa[2], m2s * xa[3]);
            a2.u[2] = cvt_pk_bf16(m2s * xb[0], m2s * xb[1]);
            a2.u[3] = cvt_pk_bf16(m2s * xb[2], m2s * xb[3]);
            bf16x8 bg = BL[(16 + ks) * 64 + lane];
            #pragma unroll
            for (int ct = 0; ct < 4; ++ct)
                acc1[ct] = __builtin_amdgcn_mfma_f32_16x16x32_bf16(a1.v, BL[(ct * 2 + ks) * 64 + lane], acc1[ct], 0, 0, 0);
            #pragma unroll
            for (int ct = 0; ct < 4; ++ct)
                acc2[ct] = __builtin_amdgcn_mfma_f32_16x16x32_bf16(a2.v, BL[((4 + ct) * 2 + ks) * 64 + lane], acc2[ct], 0, 0, 0);
            acc3 = __builtin_amdgcn_mfma_f32_16x16x32_bf16(a2.v, bg, acc3, 0, 0, 0);
        }
        __builtin_amdgcn_sched_barrier(0);
        __builtin_amdgcn_s_barrier();                        // reads done: next stage may overwrite
        __builtin_amdgcn_sched_barrier(0);
    }
#undef STAGE

    // ---- epilogue: C/D layout col=lane&15, row=(lane>>4)*4+reg ----
    int col = lane & 15;
    int rg  = lane >> 4;
    float bias = (col < HID) ? bl[col] : br[col - HID];
    float part = 0.f;
    #pragma unroll
    for (int r = 0; r < 4; ++r) {
        int row = rbase + rg * 4 + r;
        if (row < N_CELLS) {
            float s2 = S[row];
            glr[(size_t)row * 16 + col] = acc3[r] / (-2.0f * s2) + bias;
            float ss = s2 * s2;
            #pragma unroll
            for (int ct = 0; ct < 4; ++ct) {
                int c = ct * 16 + col;
                if (c < N_CLASSES) {
                    float F = -0.5f * (acc1[ct][r] + acc2[ct][r] + ss * t3[c]);
                    part = fmaf(P[(size_t)row * N_CLASSES + c], F, part);
                }
            }
        }
    }
    #pragma unroll
    for (int off = 32; off; off >>= 1) part += __shfl_xor(part, off);
    if (lane == 0) wsum[wv] = part;
    __syncthreads();
    if (tid == 0) llp[blockIdx.x] = wsum[0] + wsum[1] + wsum[2] + wsum[3];
}

// ---------- edge scores + segment max ----------
__device__ __forceinline__ unsigned map_f32(float f) {
    int s = __float_as_int(f);
    return (s < 0) ? ~(unsigned)s : ((unsigned)s | 0x80000000u);
}
__device__ __forceinline__ float unmap_f32(unsigned u) {
    return (u & 0x80000000u) ? __int_as_float((int)(u & 0x7fffffffu))
                             : __int_as_float((int)~u);
}

__global__ __launch_bounds__(256) void k_score(const int* __restrict__ ei,
                                               const float* __restrict__ glr,
                                               const float* __restrict__ att,
                                               float* __restrict__ score,
                                               unsigned* __restrict__ mseg) {
    int e = blockIdx.x * 256 + threadIdx.x;
    if (e >= N_EDGES) return;
    int src = ei[e], dst = ei[N_EDGES + e];
    const float4* a = (const float4*)(glr + (size_t)src * 16);       // gl
    const float4* b = (const float4*)(glr + (size_t)dst * 16 + 8);   // gr
    float4 g0 = a[0], g1 = a[1], h0 = b[0], h1 = b[1];
    const float4* at = (const float4*)att;
    float4 a0 = at[0], a1 = at[1];
    float v, s = 0.f;
    v = g0.x + h0.x; v = v > 0.f ? v : 0.2f * v; s = fmaf(a0.x, v, s);
    v = g0.y + h0.y; v = v > 0.f ? v : 0.2f * v; s = fmaf(a0.y, v, s);
    v = g0.z + h0.z; v = v > 0.f ? v : 0.2f * v; s = fmaf(a0.z, v, s);
    v = g0.w + h0.w; v = v > 0.f ? v : 0.2f * v; s = fmaf(a0.w, v, s);
    v = g1.x + h1.x; v = v > 0.f ? v : 0.2f * v; s = fmaf(a1.x, v, s);
    v = g1.y + h1.y; v = v > 0.f ? v : 0.2f * v; s = fmaf(a1.y, v, s);
    v = g1.z + h1.z; v = v > 0.f ? v : 0.2f * v; s = fmaf(a1.z, v, s);
    v = g1.w + h1.w; v = v > 0.f ? v : 0.2f * v; s = fmaf(a1.w, v, s);
    score[e] = s;
    atomicMax(mseg + dst, map_f32(s));
}

// ---------- fused exp/segment-sum/CE gather: 16 lanes per edge ----------
__global__ __launch_bounds__(256) void k_edge2(const int* __restrict__ ei,
                                               const float* __restrict__ score,
                                               const unsigned* __restrict__ mseg,
                                               const float* __restrict__ P,
                                               float* __restrict__ denom,
                                               float* __restrict__ numer) {
    int t = blockIdx.x * 256 + threadIdx.x;
    int e = t >> 4;
    int q = t & 15;
    if (e >= N_EDGES) return;
    int src = ei[e], dst = ei[N_EDGES + e];
    float ex = expf(score[e] - unmap_f32(mseg[dst]));
    const float* Ps = P + (size_t)src * N_CLASSES;
    const float* Pd = P + (size_t)dst * N_CLASSES;
    float v = Ps[q]      * logf(Pd[q]      + 1e-8f)
            + Ps[q + 16] * logf(Pd[q + 16] + 1e-8f)
            + Ps[q + 32] * logf(Pd[q + 32] + 1e-8f);
    if (q < 2) v += Ps[q + 48] * logf(Pd[q + 48] + 1e-8f);
    v += __shfl_xor(v, 8); v += __shfl_xor(v, 4);
    v += __shfl_xor(v, 2); v += __shfl_xor(v, 1);
    if (q == 0) {
        atomicAdd(denom + dst, ex);
        atomicAdd(numer + dst, ex * v);
    }
}

// ---------- CE node reduce -> per-block partial ----------
__global__ __launch_bounds__(256) void k_ce(const float* __restrict__ denom,
                                            const float* __restrict__ numer,
                                            float* __restrict__ cep) {
    __shared__ float wsum[4];
    int n = blockIdx.x * 256 + threadIdx.x;
    float v = 0.f;
    if (n < N_CELLS) {
        float d = denom[n];
        v = (d > 0.f) ? numer[n] / d : 0.f;
    }
    #pragma unroll
    for (int off = 32; off; off >>= 1) v += __shfl_xor(v, off);
    if ((threadIdx.x & 63) == 0) wsum[threadIdx.x >> 6] = v;
    __syncthreads();
    if (threadIdx.x == 0) cep[blockIdx.x] = wsum[0] + wsum[1] + wsum[2] + wsum[3];
}

// ---------- final: reduce partials in f64, write scalars ----------
__global__ __launch_bounds__(256) void k_reduce(const float* __restrict__ llp,
                                                const float* __restrict__ cep,
                                                float* __restrict__ out) {
    __shared__ double l1[256], l2[256];
    int t = threadIdx.x;
    double s1 = 0.0, s2 = 0.0;
    for (int i = t; i < NB_FUSED; i += 256) s1 += (double)llp[i];
    for (int i = t; i < NB_CE; i += 256) s2 += (double)cep[i];
    l1[t] = s1; l2[t] = s2;
    __syncthreads();
    for (int off = 128; off; off >>= 1) {
        if (t < off) { l1[t] += l1[t + off]; l2[t] += l2[t + off]; }
        __syncthreads();
    }
    if (t == 0) {
        out[0] = (float)(l1[0] / (double)N_CELLS);
        out[1] = (float)(-l2[0] / (double)N_CELLS);
    }
}

extern "C" void kernel_launch(void* const* d_in, const int* in_sizes, int n_in,
                              void* d_out, int out_size, void* d_ws, size_t ws_size,
                              hipStream_t stream) {
    const float* X   = (const float*)d_in[0];
    const float* Mu  = (const float*)d_in[1];
    const float* Var = (const float*)d_in[2];
    const float* W   = (const float*)d_in[3];
    const float* S   = (const float*)d_in[4];
    const int*   ei  = (const int*)d_in[5];
    const float* wl  = (const float*)d_in[6];
    const float* bl  = (const float*)d_in[7];
    const float* wr  = (const float*)d_in[8];
    const float* br  = (const float*)d_in[9];
    const float* att = (const float*)d_in[10];
    float* out = (float*)d_out;
    char*  ws  = (char*)d_ws;

    ushort*   Bf    = (ushort*)(ws + OFF_BF);
    float*    t3    = (float*)(ws + OFF_T3);
    float*    glr   = (float*)(ws + OFF_GLR);
    float*    score = (float*)(ws + OFF_SCORE);
    unsigned* mseg  = (unsigned*)(ws + OFF_MSEG);
    float*    denom = (float*)(ws + OFF_DENOM);
    float*    numer = (float*)(ws + OFF_NUMER);
    float*    llp   = (float*)(ws + OFF_LLP);
    float*    cep   = (float*)(ws + OFF_CEP);
    float*    P     = out + 2;

    hipMemsetAsync(ws + ZERO_BEG, 0, ZERO_BYTES, stream);

    k_prepB  <<<288, 256, 0, stream>>>(Var, Mu, wl, wr, Bf);
    k_t3     <<<N_CLASSES, 64, 0, stream>>>(Var, Mu, t3);
    k_softmax<<<(N_CELLS * 64 + 255) / 256, 256, 0, stream>>>(W, P);
    k_fused  <<<NB_FUSED, 256, 0, stream>>>(X, S, P, Bf, t3, bl, br, glr, llp);
    k_score  <<<(N_EDGES + 255) / 256, 256, 0, stream>>>(ei, glr, att, score, mseg);
    k_edge2  <<<(N_EDGES * 16 + 255) / 256, 256, 0, stream>>>(ei, score, mseg, P, denom, numer);
    k_ce     <<<NB_CE, 256, 0, stream>>>(denom, numer, cep);
    k_reduce <<<1, 256, 0, stream>>>(llp, cep, out);
}